// Round 1
// 631.588 us; speedup vs baseline: 1.0176x; 1.0176x over previous
//
#include <hip/hip_runtime.h>
#include <hip/hip_bf16.h>
#include <stdint.h>

#define DIM    128
#define KMAX   32
#define LN_EPS 1e-5f
#define ATT_SCALE 0.17677669529663687f   // 32^-0.5
#define CAND   2048
#define WTOT   214400                    // 212992 weight f32 + 1408 param f32
#define PB     32                        // points per block in wp_out

typedef unsigned long long u64;
static __device__ __forceinline__ float bf2f(__hip_bfloat16 x) { return __bfloat162float(x); }

// ---- bit-exact replica of the np-fp32 distance pipeline (DO NOT TOUCH: passing) ----
static __device__ __forceinline__ float norm32(float x, float y, float z) {
    return __fadd_rn(__fadd_rn(__fmul_rn(x, x), __fmul_rn(y, y)), __fmul_rn(z, z));
}
static __device__ __forceinline__ float d2_32(float cx, float cy, float cz, float cw,
                                              float px, float py, float pz, float pw) {
    float dot = __fmaf_rn(cz, pz, __fmaf_rn(cy, py, __fmul_rn(cx, px)));
    return __fsub_rn(__fadd_rn(cw, pw), __fmul_rn(2.0f, dot));
}
static __device__ __forceinline__ float d2_to_dist(float d2) {
    d2 = fmaxf(d2, 0.0f);
    return (d2 > 0.0f) ? __fsqrt_rn(d2) : 0.0f;
}
static __device__ __forceinline__ float dist32(float cx, float cy, float cz, float cw,
                                               float px, float py, float pz, float pw) {
    return d2_to_dist(d2_32(cx, cy, cz, cw, px, py, pz, pw));
}

static __device__ __forceinline__ float ldf(const void* p, int f32, size_t i) {
    return f32 ? ((const float*)p)[i] : bf2f(((const __hip_bfloat16*)p)[i]);
}
static __device__ __forceinline__ int ldidx(const void* p, int i64, int m) {
    return i64 ? ((const int*)p)[2 * m] : ((const int*)p)[m];
}

struct Ptrs { const void* p[18]; int sz[18]; };

// ---------- probe: classify each input's dtype on-device (unchanged, passing) ----------
__global__ void probe_dtypes(Ptrs P, int* __restrict__ fl) {
    int j = threadIdx.x;
    if (j >= 18) return;
    const void* x = P.p[j];
    int sz = P.sz[j];
    int flag = 0;
    if (j == 17) {
        const int* ip = (const int*)x;
        int odd_zero = 1, even_nz = 0;
        for (int k = 0; k < 8 && 2 * k + 1 < sz * 2; ++k) {
            if (ip[2 * k + 1] != 0) odd_zero = 0;
            if (ip[2 * k] != 0) even_nz = 1;
        }
        flag = (odd_zero && even_nz) ? 1 : 0;
    } else {
        const __hip_bfloat16* hp = (const __hip_bfloat16*)x;
        int n = sz < 256 ? sz : 256;
        for (int i = 0; i < n; ++i) {
            float w = bf2f(hp[i]);
            if (w != w || fabsf(w) > 1000.0f) { flag = 1; break; }
        }
        if ((j == 7 || j == 9) && bf2f(hp[0]) == 0.0f) flag = 1;
    }
    fl[j] = flag;
}

// ---------- convert weights+params -> canonical fp32 (unchanged) ----------
__global__ __launch_bounds__(256) void conv_params(Ptrs P, const int* __restrict__ fl,
                                                   float* __restrict__ Wf) {
    int i = blockIdx.x * 256 + threadIdx.x;
    if (i >= WTOT) return;
    int j, off;
    if      (i < 16384)  { j = 2;  off = i; }
    else if (i < 32768)  { j = 3;  off = i - 16384; }
    else if (i < 49152)  { j = 4;  off = i - 32768; }
    else if (i < 65536)  { j = 5;  off = i - 49152; }
    else if (i < 131072) { j = 11; off = i - 65536; }
    else if (i < 196608) { j = 13; off = i - 131072; }
    else if (i < 212992) { j = 15; off = i - 196608; }
    else if (i < 213120) { j = 6;  off = i - 212992; }
    else if (i < 213248) { j = 7;  off = i - 213120; }
    else if (i < 213376) { j = 8;  off = i - 213248; }
    else if (i < 213504) { j = 9;  off = i - 213376; }
    else if (i < 213632) { j = 10; off = i - 213504; }
    else if (i < 214144) { j = 12; off = i - 213632; }
    else if (i < 214272) { j = 14; off = i - 214144; }
    else                 { j = 16; off = i - 214272; }
    Wf[i] = ldf(P.p[j], fl[j], off);
}

__global__ void prep_pts(const void* __restrict__ xyz, const int* __restrict__ fl,
                         float4* __restrict__ pnt4, int N) {
    int i = blockIdx.x * 256 + threadIdx.x;
    if (i < N) {
        int f = fl[0];
        float x = ldf(xyz, f, 3 * i + 0), y = ldf(xyz, f, 3 * i + 1), z = ldf(xyz, f, 3 * i + 2);
        pnt4[i] = make_float4(x, y, z, norm32(x, y, z));
    }
}

__global__ void prep_ctrs(const void* __restrict__ idxc, const int* __restrict__ fl,
                          const float4* __restrict__ pnt4, float4* __restrict__ cent4,
                          int M, int N) {
    int m = blockIdx.x * 256 + threadIdx.x;
    if (m < M) {
        int c = ldidx(idxc, fl[17], m);
        c = (c >= 0 && c < N) ? c : 0;
        cent4[m] = pnt4[c];
    }
}

// =================== kernel: ball query scan + top-32 select -> nbr_g (unchanged) ===================
__global__ __launch_bounds__(256) void ball_scan(
    const float4* __restrict__ pnt4,
    const float4* __restrict__ cent4,
    int N, int* __restrict__ nbr_g) {

    __shared__ u64 key[CAND];        // 16 KB
    __shared__ int s_cnt, s_ni[KMAX];

    int m = blockIdx.x, tid = threadIdx.x;
    float4 cc4 = cent4[m];

    if (tid == 0) s_cnt = 0;
    if (tid < KMAX) s_ni[tid] = -1;
    __syncthreads();

    for (int i = tid; i < N; i += 256) {
        float4 p = pnt4[i];
        float d2 = d2_32(cc4.x, cc4.y, cc4.z, cc4.w, p.x, p.y, p.z, p.w);
        if (d2 < 0.0901f) {
            float dist = d2_to_dist(d2);
            if (dist < 0.3f) {
                int pos = atomicAdd(&s_cnt, 1);
                if (pos < CAND)
                    key[pos] = ((u64)__float_as_uint(dist) << 32) | (unsigned)i;
            }
        }
    }
    __syncthreads();
    int cnt = min(s_cnt, CAND);

    for (int i = tid; i < cnt; i += 256) {
        u64 ki = key[i];
        int r = 0;
        for (int j = 0; j < cnt; ++j) r += (key[j] < ki) ? 1 : 0;
        if (r < KMAX) s_ni[r] = (int)(unsigned)(ki & 0xFFFFFFFFULL);
    }
    __syncthreads();
    if (tid < KMAX) nbr_g[m * KMAX + tid] = s_ni[tid];
}

// =================== kernel: attention + FFN -> cf (unchanged, passing) ===================
__global__ __launch_bounds__(256) void attn_ffn(
    const int* __restrict__ nbr_g,
    const void* __restrict__ feats,
    const void* __restrict__ idxc,
    const int* __restrict__ fl,
    const float* __restrict__ Wf,
    float* __restrict__ cf_out, int N) {

    const float* Wqf = Wf;
    const float* Wkf = Wf + 16384;
    const float* Wvf = Wf + 32768;
    const float* Wof = Wf + 49152;
    const float* W1f = Wf + 65536;
    const float* W2f = Wf + 131072;
    const float* Pf  = Wf + 212992;

    __shared__ __align__(16) float nft[DIM][33];
    __shared__ float s_kv[KMAX][130];
    __shared__ int   s_ni[KMAX];
    __shared__ __align__(16) float s_cf[DIM], s_q[DIM], s_attn[DIM], s_ao[DIM], s_x[DIM];
    __shared__ float s_tree[128], s_part[256];
    __shared__ float s_hmax[4], s_hsum[4];

    int m = blockIdx.x, tid = threadIdx.x;
    int f1 = fl[1];
    int c = ldidx(idxc, fl[17], m);
    c = (c >= 0 && c < N) ? c : 0;

    if (tid < KMAX) s_ni[tid] = nbr_g[m * KMAX + tid];
    if (tid < 128) s_cf[tid] = ldf(feats, f1, (size_t)c * DIM + tid);
    __syncthreads();
    for (int t = tid; t < KMAX * DIM; t += 256) {
        int kk = t >> 7, cc = t & 127;
        int idx = s_ni[kk];
        float v = (idx >= 0 && idx < N) ? ldf(feats, f1, (size_t)idx * DIM + cc) : 0.0f;
        nft[cc][kk] = v;
    }
    __syncthreads();

    if (tid < 128) {
        float acc = 0.0f;
#pragma unroll 4
        for (int i = 0; i < DIM; i += 4) {
            float4 a = *(const float4*)&s_cf[i];
            acc = fmaf(a.x, Wqf[(i + 0) * DIM + tid], acc);
            acc = fmaf(a.y, Wqf[(i + 1) * DIM + tid], acc);
            acc = fmaf(a.z, Wqf[(i + 2) * DIM + tid], acc);
            acc = fmaf(a.w, Wqf[(i + 3) * DIM + tid], acc);
        }
        s_q[tid] = acc;
    }

    int mat = tid >> 7, col = tid & 127;
    const float* Wm = mat ? Wvf : Wkf;
    float acc[KMAX];
#pragma unroll
    for (int kk = 0; kk < KMAX; ++kk) acc[kk] = 0.0f;
    for (int i = 0; i < DIM; ++i) {
        float w = Wm[i * DIM + col];
#pragma unroll
        for (int k4 = 0; k4 < 8; ++k4) {
            float4 n = *(const float4*)&nft[i][k4 * 4];
            acc[k4 * 4 + 0] = fmaf(n.x, w, acc[k4 * 4 + 0]);
            acc[k4 * 4 + 1] = fmaf(n.y, w, acc[k4 * 4 + 1]);
            acc[k4 * 4 + 2] = fmaf(n.z, w, acc[k4 * 4 + 2]);
            acc[k4 * 4 + 3] = fmaf(n.w, w, acc[k4 * 4 + 3]);
        }
    }
    if (mat == 0) {
#pragma unroll
        for (int kk = 0; kk < KMAX; ++kk) s_kv[kk][col] = acc[kk];
    }
    __syncthreads();

    if (tid < 128) {
        int h = tid >> 5, kk = tid & 31;
        float s = 0.0f;
#pragma unroll
        for (int d = 0; d < 32; ++d)
            s = fmaf(s_q[h * 32 + d], s_kv[kk][h * 32 + d], s);
        s *= ATT_SCALE;
        if (s_ni[kk] < 0) s = -1e9f;
        s_attn[tid] = s;
    }
    __syncthreads();
    if (tid < 4) {
        float mx = -3.4e38f;
        for (int kk = 0; kk < 32; ++kk) mx = fmaxf(mx, s_attn[tid * 32 + kk]);
        float sm = 0.0f;
        for (int kk = 0; kk < 32; ++kk) sm += expf(s_attn[tid * 32 + kk] - mx);
        s_hmax[tid] = mx;
        s_hsum[tid] = (sm > 0.0f) ? sm : 1.0f;
    }
    __syncthreads();
    if (tid < 128)
        s_attn[tid] = expf(s_attn[tid] - s_hmax[tid >> 5]) / s_hsum[tid >> 5];
    __syncthreads();

    if (mat == 1) {
#pragma unroll
        for (int kk = 0; kk < KMAX; ++kk) s_kv[kk][col] = acc[kk];
    }
    __syncthreads();

    if (tid < 128) {
        int h = tid >> 5, d = tid & 31;
        float o = 0.0f;
#pragma unroll
        for (int kk = 0; kk < KMAX; ++kk)
            o = fmaf(s_attn[h * 32 + kk], s_kv[kk][h * 32 + d], o);
        s_ao[d * 4 + h] = o;
    }
    __syncthreads();

    float upd = 0.0f;
    if (tid < 128) {
        upd = Pf[0 + tid];  // bo
#pragma unroll 4
        for (int i = 0; i < DIM; i += 4) {
            float4 a = *(const float4*)&s_ao[i];
            upd = fmaf(a.x, Wof[(i + 0) * DIM + tid], upd);
            upd = fmaf(a.y, Wof[(i + 1) * DIM + tid], upd);
            upd = fmaf(a.z, Wof[(i + 2) * DIM + tid], upd);
            upd = fmaf(a.w, Wof[(i + 3) * DIM + tid], upd);
        }
    }
    if (tid < 128) s_tree[tid] = upd;
    __syncthreads();
    for (int s = 64; s > 0; s >>= 1) { if (tid < s) s_tree[tid] += s_tree[tid + s]; __syncthreads(); }
    float mu = s_tree[0] * (1.0f / 128.0f);
    __syncthreads();
    float xc = upd - mu;
    if (tid < 128) s_tree[tid] = xc * xc;
    __syncthreads();
    for (int s = 64; s > 0; s >>= 1) { if (tid < s) s_tree[tid] += s_tree[tid + s]; __syncthreads(); }
    float var = s_tree[0] * (1.0f / 128.0f);
    __syncthreads();
    float cf1 = 0.0f;
    if (tid < 128) {
        float rs = 1.0f / sqrtf(var + LN_EPS);
        float ln1 = fmaf(xc * rs, Pf[128 + tid], Pf[256 + tid]);  // n1w, n1b
        cf1 = s_cf[tid] + ln1;
        s_x[tid] = cf1;
    }
    __syncthreads();

    float* s_h = (float*)&nft[0][0];
#pragma unroll
    for (int jj = 0; jj < 2; ++jj) {
        int j = jj * 256 + tid;
        float a = Pf[640 + j];  // b1
#pragma unroll 4
        for (int i = 0; i < DIM; i += 4) {
            float4 v = *(const float4*)&s_x[i];
            a = fmaf(v.x, W1f[(i + 0) * 512 + j], a);
            a = fmaf(v.y, W1f[(i + 1) * 512 + j], a);
            a = fmaf(v.z, W1f[(i + 2) * 512 + j], a);
            a = fmaf(v.w, W1f[(i + 3) * 512 + j], a);
        }
        s_h[j] = fmaxf(a, 0.0f);
    }
    __syncthreads();

    int half = tid >> 7;
    float f2 = (half == 0) ? Pf[1152 + col] : 0.0f;  // b2
    {
        int i0 = half * 256;
#pragma unroll 4
        for (int i = i0; i < i0 + 256; i += 4) {
            float4 v = *(const float4*)&s_h[i];
            f2 = fmaf(v.x, W2f[(i + 0) * DIM + col], f2);
            f2 = fmaf(v.y, W2f[(i + 1) * DIM + col], f2);
            f2 = fmaf(v.z, W2f[(i + 2) * DIM + col], f2);
            f2 = fmaf(v.w, W2f[(i + 3) * DIM + col], f2);
        }
    }
    s_part[tid] = f2;
    __syncthreads();
    float ffn = 0.0f;
    if (tid < 128) ffn = s_part[tid] + s_part[tid + 128];
    if (tid < 128) s_tree[tid] = ffn;
    __syncthreads();
    for (int s = 64; s > 0; s >>= 1) { if (tid < s) s_tree[tid] += s_tree[tid + s]; __syncthreads(); }
    mu = s_tree[0] * (1.0f / 128.0f);
    __syncthreads();
    xc = ffn - mu;
    if (tid < 128) s_tree[tid] = xc * xc;
    __syncthreads();
    for (int s = 64; s > 0; s >>= 1) { if (tid < s) s_tree[tid] += s_tree[tid + s]; __syncthreads(); }
    var = s_tree[0] * (1.0f / 128.0f);
    __syncthreads();
    if (tid < 128) {
        float rs2 = 1.0f / sqrtf(var + LN_EPS);
        float ln2 = fmaf(xc * rs2, Pf[384 + tid], Pf[512 + tid]);  // n2w, n2b
        cf_out[(size_t)m * DIM + tid] = cf1 + ln2;
    }
}

// =================== kernel: wave-per-point KNN select + upsample -> up (stored in d_out) ===================
// Identical scan/merge/weight math to the proven knn_fused (fast top-3 chain with exactness
// fallback). The Wp GEMM + epilogue are MOVED to wp_out; this kernel ends by storing the
// exact up vector (same fma order) into out[], which wp_out consumes in place.
#define CSWAP(a, b) { if ((b) < (a)) { u64 t_ = (a); (a) = (b); (b) = t_; } }

__global__ __launch_bounds__(256) void knn_select(
    const float4* __restrict__ pnt4,
    const float4* __restrict__ cent4,
    const float* __restrict__ cf,
    float* __restrict__ upg,          // = d_out, N x 128 f32
    int N, int M) {

    int lane = threadIdx.x & 63;
    int wv   = threadIdx.x >> 6;
    int p = blockIdx.x * 4 + wv;
    bool own = (p < N);

    float4 pp = make_float4(0.f, 0.f, 0.f, 0.f);
    if (own) pp = pnt4[p];          // own is wave-uniform

    // ---- fast scan: per-lane top-3 ----
    u64 b0 = ~0ULL, b1 = ~0ULL, b2 = ~0ULL;
    for (int j = lane; j < M; j += 64) {
        float4 cc = cent4[j];
        float dist = dist32(cc.x, cc.y, cc.z, cc.w, pp.x, pp.y, pp.z, pp.w);
        u64 key = ((u64)__float_as_uint(dist) << 32) | (unsigned)j;
        if (key < b2) {
            b2 = key;
            CSWAP(b1, b2); CSWAP(b0, b1);
        }
    }

    // ---- ascending merge from top-3 heads ----
    int   ptr = 0;
    u64   cur = b0;
    float wsum = 0.0f;
    int   ki[8];
    float w8[8];
#pragma unroll
    for (int e = 0; e < 8; ++e) {
        u64 v = cur;
        for (int off = 32; off; off >>= 1) {
            u64 o = __shfl_down(v, off, 64);
            v = (o < v) ? o : v;
        }
        u64 gm = __shfl(v, 0, 64);                 // global min, broadcast
        float d = __uint_as_float((unsigned)(gm >> 32));
        int ci = (int)(unsigned)(gm & 0xFFFFFFFFULL);
        ci = (ci >= 0 && ci < M) ? ci : 0;
        float t = __fadd_rn(d, 1e-6f);
        float w = 1.0f / __fmul_rn(t, t);
        wsum += w;                                 // ascending-order sum (bit-exact)
        ki[e] = ci;
        w8[e] = w;
        if (cur == gm) {                           // unique owner advances
            ptr++;
            cur = (ptr == 1) ? b1 : (ptr == 2) ? b2 : ~0ULL;
        }
    }

    // ---- exactness check: any lane exhausted its 3 -> full 8-deep rescan ----
    if (__ballot(ptr >= 3) != 0ULL) {
        u64 f0 = ~0ULL, f1_ = ~0ULL, f2_ = ~0ULL, f3 = ~0ULL,
            f4 = ~0ULL, f5 = ~0ULL, f6 = ~0ULL, f7 = ~0ULL;
        for (int j = lane; j < M; j += 64) {
            float4 cc = cent4[j];
            float dist = dist32(cc.x, cc.y, cc.z, cc.w, pp.x, pp.y, pp.z, pp.w);
            u64 key = ((u64)__float_as_uint(dist) << 32) | (unsigned)j;
            if (key < f7) {
                f7 = key;
                CSWAP(f6, f7); CSWAP(f5, f6); CSWAP(f4, f5); CSWAP(f3, f4);
                CSWAP(f2_, f3); CSWAP(f1_, f2_); CSWAP(f0, f1_);
            }
        }
        int ptr2 = 0;
        u64 cur2 = f0;
        wsum = 0.0f;
#pragma unroll
        for (int e = 0; e < 8; ++e) {
            u64 v = cur2;
            for (int off = 32; off; off >>= 1) {
                u64 o = __shfl_down(v, off, 64);
                v = (o < v) ? o : v;
            }
            u64 gm = __shfl(v, 0, 64);
            float d = __uint_as_float((unsigned)(gm >> 32));
            int ci = (int)(unsigned)(gm & 0xFFFFFFFFULL);
            ci = (ci >= 0 && ci < M) ? ci : 0;
            float t = __fadd_rn(d, 1e-6f);
            float w = 1.0f / __fmul_rn(t, t);
            wsum += w;
            ki[e] = ci;
            w8[e] = w;
            if (cur2 == gm) {
                ptr2++;
                cur2 = (ptr2 == 1) ? f1_ : (ptr2 == 2) ? f2_ : (ptr2 == 3) ? f3 :
                       (ptr2 == 4) ? f4 : (ptr2 == 5) ? f5 : (ptr2 == 6) ? f6 :
                       (ptr2 == 7) ? f7 : ~0ULL;
            }
        }
    }

    float inv = 1.0f / wsum;
#pragma unroll
    for (int e = 0; e < 8; ++e) w8[e] *= inv;

    // ---- upsample: lane owns cols lane and lane+64 (k ascending, bit-exact) ----
    int c0 = lane, c1 = lane + 64;
    float up0 = 0.0f, up1 = 0.0f;
#pragma unroll
    for (int k = 0; k < 8; ++k) {
        const float* row = cf + (size_t)ki[k] * DIM;
        up0 = fmaf(w8[k], row[c0], up0);
        up1 = fmaf(w8[k], row[c1], up1);
    }

    if (own) {
        upg[(size_t)p * DIM + c0] = up0;
        upg[(size_t)p * DIM + c1] = up1;
    }
}

// =================== kernel: tiled Wp GEMM + epilogue, in place over d_out ===================
// out[p][c] = feats[p][c] + up[p][c] + relu(bp[c] + sum_i up[p][i]*Wp[i][c])
// fma chain over i = 0..127 ascending, acc starts at 0, bias added after -> identical
// operation sequence to the previous per-column loop (bit-exact). Each block stages its
// own 32 rows of up into LDS before overwriting them, so in-place is race-free.
__global__ __launch_bounds__(256) void wp_out(
    const float* __restrict__ Wf,
    const void* __restrict__ feats,
    const int* __restrict__ fl,
    float* __restrict__ out,          // holds up on entry, final output on exit
    int N) {

    const float* Wpf = Wf + 196608;
    const float* bpf = Wf + 212992 + 1280;

    __shared__ __align__(16) float s_up[PB][132];   // +4 pad: 16B-aligned rows, bank spread

    int tid = threadIdx.x;
    int p0 = blockIdx.x * PB;

    // stage up tile (32 pts x 128), zero-fill past N
    for (int f = tid; f < PB * 32; f += 256) {
        int p = f >> 5, i4 = (f & 31) << 2;
        float4 v = make_float4(0.f, 0.f, 0.f, 0.f);
        if (p0 + p < N) v = *(const float4*)&out[(size_t)(p0 + p) * DIM + i4];
        *(float4*)&s_up[p][i4] = v;
    }
    __syncthreads();

    // thread = 4 cols x 4 pts register tile
    int cq = tid & 31, pq = tid >> 5;
    int c0 = cq << 2;
    int pA = pq << 2;

    float a00 = 0.f, a01 = 0.f, a02 = 0.f, a03 = 0.f;
    float a10 = 0.f, a11 = 0.f, a12 = 0.f, a13 = 0.f;
    float a20 = 0.f, a21 = 0.f, a22 = 0.f, a23 = 0.f;
    float a30 = 0.f, a31 = 0.f, a32 = 0.f, a33 = 0.f;

#pragma unroll 4
    for (int i = 0; i < DIM; ++i) {
        float4 w = *(const float4*)&Wpf[(size_t)i * DIM + c0];
        float u0 = s_up[pA + 0][i];
        float u1 = s_up[pA + 1][i];
        float u2 = s_up[pA + 2][i];
        float u3 = s_up[pA + 3][i];
        a00 = fmaf(u0, w.x, a00); a01 = fmaf(u0, w.y, a01);
        a02 = fmaf(u0, w.z, a02); a03 = fmaf(u0, w.w, a03);
        a10 = fmaf(u1, w.x, a10); a11 = fmaf(u1, w.y, a11);
        a12 = fmaf(u1, w.z, a12); a13 = fmaf(u1, w.w, a13);
        a20 = fmaf(u2, w.x, a20); a21 = fmaf(u2, w.y, a21);
        a22 = fmaf(u2, w.z, a22); a23 = fmaf(u2, w.w, a23);
        a30 = fmaf(u3, w.x, a30); a31 = fmaf(u3, w.y, a31);
        a32 = fmaf(u3, w.z, a32); a33 = fmaf(u3, w.w, a33);
    }

    int f1v = fl[1];
    float4 bp4 = make_float4(bpf[c0 + 0], bpf[c0 + 1], bpf[c0 + 2], bpf[c0 + 3]);

    float accs[4][4] = {{a00, a01, a02, a03}, {a10, a11, a12, a13},
                        {a20, a21, a22, a23}, {a30, a31, a32, a33}};
#pragma unroll
    for (int a = 0; a < 4; ++a) {
        int p = p0 + pA + a;
        if (p < N) {
            float4 u = *(const float4*)&s_up[pA + a][c0];
            float4 o;
            o.x = ldf(feats, f1v, (size_t)p * DIM + c0 + 0) + u.x + fmaxf(bp4.x + accs[a][0], 0.0f);
            o.y = ldf(feats, f1v, (size_t)p * DIM + c0 + 1) + u.y + fmaxf(bp4.y + accs[a][1], 0.0f);
            o.z = ldf(feats, f1v, (size_t)p * DIM + c0 + 2) + u.z + fmaxf(bp4.z + accs[a][2], 0.0f);
            o.w = ldf(feats, f1v, (size_t)p * DIM + c0 + 3) + u.w + fmaxf(bp4.w + accs[a][3], 0.0f);
            *(float4*)&out[(size_t)p * DIM + c0] = o;
        }
    }
}

extern "C" void kernel_launch(void* const* d_in, const int* in_sizes, int n_in,
                              void* d_out, int out_size, void* d_ws, size_t ws_size,
                              hipStream_t stream) {
    int N = in_sizes[0] / 3;
    int M = in_sizes[17];

    Ptrs P;
    for (int j = 0; j < 18; ++j) { P.p[j] = d_in[j]; P.sz[j] = in_sizes[j]; }

    size_t off = 0;
    auto alloc = [&](size_t bytes) -> void* {
        off = (off + 255) & ~(size_t)255;
        void* p = (void*)((char*)d_ws + off);
        off += bytes;
        return p;
    };
    int*    fl    = (int*)alloc(32 * 4);
    float*  Wf    = (float*)alloc((size_t)WTOT * 4);          // 858 KB
    float4* pnt4  = (float4*)alloc((size_t)N * 16);           // 800 KB
    float4* cent4 = (float4*)alloc((size_t)M * 16);           //  40 KB
    float*  cfbuf = (float*)alloc((size_t)M * DIM * 4);       // 1.28 MB
    int*    nbr   = (int*)alloc((size_t)M * KMAX * 4);        // 320 KB (total ~3.3 MB)

    probe_dtypes<<<1, 32, 0, stream>>>(P, fl);
    conv_params<<<(WTOT + 255) / 256, 256, 0, stream>>>(P, fl, Wf);
    prep_pts<<<(N + 255) / 256, 256, 0, stream>>>(d_in[0], fl, pnt4, N);
    prep_ctrs<<<(M + 255) / 256, 256, 0, stream>>>(d_in[17], fl, pnt4, cent4, M, N);
    ball_scan<<<M, 256, 0, stream>>>(pnt4, cent4, N, nbr);
    attn_ffn<<<M, 256, 0, stream>>>(nbr, d_in[1], d_in[17], fl, Wf, cfbuf, N);
    knn_select<<<(N + 3) / 4, 256, 0, stream>>>(pnt4, cent4, cfbuf, (float*)d_out, N, M);
    wp_out<<<(N + PB - 1) / PB, 256, 0, stream>>>(Wf, d_in[1], fl, (float*)d_out, N);
}

// Round 2
// 624.827 us; speedup vs baseline: 1.0286x; 1.0108x over previous
//
#include <hip/hip_runtime.h>
#include <hip/hip_bf16.h>
#include <stdint.h>

#define DIM    128
#define KMAX   32
#define LN_EPS 1e-5f
#define ATT_SCALE 0.17677669529663687f   // 32^-0.5
#define CAND   2048
#define WTOT   214400                    // 212992 weight f32 + 1408 param f32
#define PB     32                        // points per block in wp_out

typedef unsigned long long u64;
static __device__ __forceinline__ float bf2f(__hip_bfloat16 x) { return __bfloat162float(x); }

// ---- bit-exact replica of the np-fp32 distance pipeline (DO NOT TOUCH: passing) ----
static __device__ __forceinline__ float norm32(float x, float y, float z) {
    return __fadd_rn(__fadd_rn(__fmul_rn(x, x), __fmul_rn(y, y)), __fmul_rn(z, z));
}
static __device__ __forceinline__ float d2_32(float cx, float cy, float cz, float cw,
                                              float px, float py, float pz, float pw) {
    float dot = __fmaf_rn(cz, pz, __fmaf_rn(cy, py, __fmul_rn(cx, px)));
    return __fsub_rn(__fadd_rn(cw, pw), __fmul_rn(2.0f, dot));
}
static __device__ __forceinline__ float d2_to_dist(float d2) {
    d2 = fmaxf(d2, 0.0f);
    return (d2 > 0.0f) ? __fsqrt_rn(d2) : 0.0f;
}
static __device__ __forceinline__ float dist32(float cx, float cy, float cz, float cw,
                                               float px, float py, float pz, float pw) {
    return d2_to_dist(d2_32(cx, cy, cz, cw, px, py, pz, pw));
}

static __device__ __forceinline__ float ldf(const void* p, int f32, size_t i) {
    return f32 ? ((const float*)p)[i] : bf2f(((const __hip_bfloat16*)p)[i]);
}
static __device__ __forceinline__ int ldidx(const void* p, int i64, int m) {
    return i64 ? ((const int*)p)[2 * m] : ((const int*)p)[m];
}

struct Ptrs { const void* p[18]; int sz[18]; };

// ---------- probe: classify each input's dtype on-device (unchanged, passing) ----------
__global__ void probe_dtypes(Ptrs P, int* __restrict__ fl) {
    int j = threadIdx.x;
    if (j >= 18) return;
    const void* x = P.p[j];
    int sz = P.sz[j];
    int flag = 0;
    if (j == 17) {
        const int* ip = (const int*)x;
        int odd_zero = 1, even_nz = 0;
        for (int k = 0; k < 8 && 2 * k + 1 < sz * 2; ++k) {
            if (ip[2 * k + 1] != 0) odd_zero = 0;
            if (ip[2 * k] != 0) even_nz = 1;
        }
        flag = (odd_zero && even_nz) ? 1 : 0;
    } else {
        const __hip_bfloat16* hp = (const __hip_bfloat16*)x;
        int n = sz < 256 ? sz : 256;
        for (int i = 0; i < n; ++i) {
            float w = bf2f(hp[i]);
            if (w != w || fabsf(w) > 1000.0f) { flag = 1; break; }
        }
        if ((j == 7 || j == 9) && bf2f(hp[0]) == 0.0f) flag = 1;
    }
    fl[j] = flag;
}

// ---------- convert weights+params -> canonical fp32 (unchanged) ----------
__global__ __launch_bounds__(256) void conv_params(Ptrs P, const int* __restrict__ fl,
                                                   float* __restrict__ Wf) {
    int i = blockIdx.x * 256 + threadIdx.x;
    if (i >= WTOT) return;
    int j, off;
    if      (i < 16384)  { j = 2;  off = i; }
    else if (i < 32768)  { j = 3;  off = i - 16384; }
    else if (i < 49152)  { j = 4;  off = i - 32768; }
    else if (i < 65536)  { j = 5;  off = i - 49152; }
    else if (i < 131072) { j = 11; off = i - 65536; }
    else if (i < 196608) { j = 13; off = i - 131072; }
    else if (i < 212992) { j = 15; off = i - 196608; }
    else if (i < 213120) { j = 6;  off = i - 212992; }
    else if (i < 213248) { j = 7;  off = i - 213120; }
    else if (i < 213376) { j = 8;  off = i - 213248; }
    else if (i < 213504) { j = 9;  off = i - 213376; }
    else if (i < 213632) { j = 10; off = i - 213504; }
    else if (i < 214144) { j = 12; off = i - 213632; }
    else if (i < 214272) { j = 14; off = i - 214144; }
    else                 { j = 16; off = i - 214272; }
    Wf[i] = ldf(P.p[j], fl[j], off);
}

__global__ void prep_pts(const void* __restrict__ xyz, const int* __restrict__ fl,
                         float4* __restrict__ pnt4, int N) {
    int i = blockIdx.x * 256 + threadIdx.x;
    if (i < N) {
        int f = fl[0];
        float x = ldf(xyz, f, 3 * i + 0), y = ldf(xyz, f, 3 * i + 1), z = ldf(xyz, f, 3 * i + 2);
        pnt4[i] = make_float4(x, y, z, norm32(x, y, z));
    }
}

__global__ void prep_ctrs(const void* __restrict__ idxc, const int* __restrict__ fl,
                          const float4* __restrict__ pnt4, float4* __restrict__ cent4,
                          int M, int N) {
    int m = blockIdx.x * 256 + threadIdx.x;
    if (m < M) {
        int c = ldidx(idxc, fl[17], m);
        c = (c >= 0 && c < N) ? c : 0;
        cent4[m] = pnt4[c];
    }
}

// =================== kernel: ball query scan + top-32 select -> nbr_g (unchanged) ===================
__global__ __launch_bounds__(256) void ball_scan(
    const float4* __restrict__ pnt4,
    const float4* __restrict__ cent4,
    int N, int* __restrict__ nbr_g) {

    __shared__ u64 key[CAND];        // 16 KB
    __shared__ int s_cnt, s_ni[KMAX];

    int m = blockIdx.x, tid = threadIdx.x;
    float4 cc4 = cent4[m];

    if (tid == 0) s_cnt = 0;
    if (tid < KMAX) s_ni[tid] = -1;
    __syncthreads();

    for (int i = tid; i < N; i += 256) {
        float4 p = pnt4[i];
        float d2 = d2_32(cc4.x, cc4.y, cc4.z, cc4.w, p.x, p.y, p.z, p.w);
        if (d2 < 0.0901f) {
            float dist = d2_to_dist(d2);
            if (dist < 0.3f) {
                int pos = atomicAdd(&s_cnt, 1);
                if (pos < CAND)
                    key[pos] = ((u64)__float_as_uint(dist) << 32) | (unsigned)i;
            }
        }
    }
    __syncthreads();
    int cnt = min(s_cnt, CAND);

    for (int i = tid; i < cnt; i += 256) {
        u64 ki = key[i];
        int r = 0;
        for (int j = 0; j < cnt; ++j) r += (key[j] < ki) ? 1 : 0;
        if (r < KMAX) s_ni[r] = (int)(unsigned)(ki & 0xFFFFFFFFULL);
    }
    __syncthreads();
    if (tid < KMAX) nbr_g[m * KMAX + tid] = s_ni[tid];
}

// =================== kernel: attention + FFN -> cf ===================
// v2: LDS cut 37.9KB -> ~19.7KB by aliasing nft / s_kv / (s_h,s_part) into one region R
// (each is dead before the next is written; barriers inserted at the alias points).
// -> 8 blocks/CU instead of 4. Barrier count 34 -> 14: LN reduction trees replaced with
// __shfl_xor wave reductions, serial tid<4 softmax replaced with 32-lane shuffle reduce.
// GEMM cores, score math, masking and gather logic are UNCHANGED (same fma chains).
#define NFT(cc, kk) R[(cc) * 33 + (kk)]
#define SKV(kk, col) R[(kk) * 130 + (col)]

__global__ __launch_bounds__(256) void attn_ffn(
    const int* __restrict__ nbr_g,
    const void* __restrict__ feats,
    const void* __restrict__ idxc,
    const int* __restrict__ fl,
    const float* __restrict__ Wf,
    float* __restrict__ cf_out, int N) {

    const float* Wqf = Wf;
    const float* Wkf = Wf + 16384;
    const float* Wvf = Wf + 32768;
    const float* Wof = Wf + 49152;
    const float* W1f = Wf + 65536;
    const float* W2f = Wf + 131072;
    const float* Pf  = Wf + 212992;

    __shared__ __align__(16) float R[4224];   // 16.9KB: nft[128][33] | s_kv[32][130] | s_h[512]+s_part[256]
    __shared__ int   s_ni[KMAX];
    __shared__ __align__(16) float s_cf[DIM], s_q[DIM], s_attn[DIM], s_ao[DIM], s_x[DIM];
    __shared__ float s_red[4];

    int m = blockIdx.x, tid = threadIdx.x;
    int lane = tid & 63, wv = tid >> 6;
    int f1 = fl[1];
    int c = ldidx(idxc, fl[17], m);
    c = (c >= 0 && c < N) ? c : 0;

    if (tid < KMAX) s_ni[tid] = nbr_g[m * KMAX + tid];
    if (tid < 128) s_cf[tid] = ldf(feats, f1, (size_t)c * DIM + tid);
    __syncthreads();                                             // B1
    for (int t = tid; t < KMAX * DIM; t += 256) {
        int kk = t >> 7, cc = t & 127;
        int idx = s_ni[kk];
        float v = (idx >= 0 && idx < N) ? ldf(feats, f1, (size_t)idx * DIM + cc) : 0.0f;
        NFT(cc, kk) = v;
    }
    __syncthreads();                                             // B2

    if (tid < 128) {
        float acc = 0.0f;
#pragma unroll 4
        for (int i = 0; i < DIM; i += 4) {
            float4 a = *(const float4*)&s_cf[i];
            acc = fmaf(a.x, Wqf[(i + 0) * DIM + tid], acc);
            acc = fmaf(a.y, Wqf[(i + 1) * DIM + tid], acc);
            acc = fmaf(a.z, Wqf[(i + 2) * DIM + tid], acc);
            acc = fmaf(a.w, Wqf[(i + 3) * DIM + tid], acc);
        }
        s_q[tid] = acc;
    }

    int mat = tid >> 7, col = tid & 127;
    const float* Wm = mat ? Wvf : Wkf;
    float acc[KMAX];
#pragma unroll
    for (int kk = 0; kk < KMAX; ++kk) acc[kk] = 0.0f;
    for (int i = 0; i < DIM; ++i) {
        float w = Wm[i * DIM + col];
#pragma unroll
        for (int k4 = 0; k4 < 8; ++k4) {
            float4 n = *(const float4*)&NFT(i, k4 * 4);
            acc[k4 * 4 + 0] = fmaf(n.x, w, acc[k4 * 4 + 0]);
            acc[k4 * 4 + 1] = fmaf(n.y, w, acc[k4 * 4 + 1]);
            acc[k4 * 4 + 2] = fmaf(n.z, w, acc[k4 * 4 + 2]);
            acc[k4 * 4 + 3] = fmaf(n.w, w, acc[k4 * 4 + 3]);
        }
    }
    __syncthreads();                                             // B3: nft reads done, R reusable
    if (mat == 0) {
#pragma unroll
        for (int kk = 0; kk < KMAX; ++kk) SKV(kk, col) = acc[kk];  // K -> R
    }
    __syncthreads();                                             // B4

    if (tid < 128) {
        int h = tid >> 5, kk = tid & 31;
        float s = 0.0f;
#pragma unroll
        for (int d = 0; d < 32; ++d)
            s = fmaf(s_q[h * 32 + d], SKV(kk, h * 32 + d), s);
        s *= ATT_SCALE;
        if (s_ni[kk] < 0) s = -1e9f;
        // per-head softmax via 32-lane shuffle reduce (head = 32 contiguous lanes)
        float mx = s;
        for (int off = 16; off; off >>= 1) mx = fmaxf(mx, __shfl_xor(mx, off, 32));
        float e = expf(s - mx);
        float sm = e;
        for (int off = 16; off; off >>= 1) sm += __shfl_xor(sm, off, 32);
        sm = (sm > 0.0f) ? sm : 1.0f;
        s_attn[tid] = e / sm;
    }
    __syncthreads();                                             // B5: attn ready, K reads done
    if (mat == 1) {
#pragma unroll
        for (int kk = 0; kk < KMAX; ++kk) SKV(kk, col) = acc[kk];  // V -> R
    }
    __syncthreads();                                             // B6

    if (tid < 128) {
        int h = tid >> 5, d = tid & 31;
        float o = 0.0f;
#pragma unroll
        for (int kk = 0; kk < KMAX; ++kk)
            o = fmaf(s_attn[h * 32 + kk], SKV(kk, h * 32 + d), o);
        s_ao[d * 4 + h] = o;
    }
    __syncthreads();                                             // B7

    float upd = 0.0f;
    if (tid < 128) {
        upd = Pf[0 + tid];  // bo
#pragma unroll 4
        for (int i = 0; i < DIM; i += 4) {
            float4 a = *(const float4*)&s_ao[i];
            upd = fmaf(a.x, Wof[(i + 0) * DIM + tid], upd);
            upd = fmaf(a.y, Wof[(i + 1) * DIM + tid], upd);
            upd = fmaf(a.z, Wof[(i + 2) * DIM + tid], upd);
            upd = fmaf(a.w, Wof[(i + 3) * DIM + tid], upd);
        }
        float sum = upd;
        for (int off = 32; off; off >>= 1) sum += __shfl_xor(sum, off, 64);
        if (lane == 0) s_red[wv] = sum;
    }
    __syncthreads();                                             // B8
    float mu = (s_red[0] + s_red[1]) * (1.0f / 128.0f);
    float xc = upd - mu;
    if (tid < 128) {
        float q2 = xc * xc;
        for (int off = 32; off; off >>= 1) q2 += __shfl_xor(q2, off, 64);
        if (lane == 0) s_red[2 + wv] = q2;
    }
    __syncthreads();                                             // B9
    float var = (s_red[2] + s_red[3]) * (1.0f / 128.0f);
    float cf1 = 0.0f;
    if (tid < 128) {
        float rs = 1.0f / sqrtf(var + LN_EPS);
        float ln1 = fmaf(xc * rs, Pf[128 + tid], Pf[256 + tid]);  // n1w, n1b
        cf1 = s_cf[tid] + ln1;
        s_x[tid] = cf1;
    }
    __syncthreads();                                             // B10

    float* s_h = R;              // R[0..512): FFN hidden
    float* s_part = R + 512;     // R[512..768): W2 partials
#pragma unroll
    for (int jj = 0; jj < 2; ++jj) {
        int j = jj * 256 + tid;
        float a = Pf[640 + j];  // b1
#pragma unroll 4
        for (int i = 0; i < DIM; i += 4) {
            float4 v = *(const float4*)&s_x[i];
            a = fmaf(v.x, W1f[(i + 0) * 512 + j], a);
            a = fmaf(v.y, W1f[(i + 1) * 512 + j], a);
            a = fmaf(v.z, W1f[(i + 2) * 512 + j], a);
            a = fmaf(v.w, W1f[(i + 3) * 512 + j], a);
        }
        s_h[j] = fmaxf(a, 0.0f);
    }
    __syncthreads();                                             // B11

    int half = tid >> 7;
    float f2 = (half == 0) ? Pf[1152 + col] : 0.0f;  // b2
    {
        int i0 = half * 256;
#pragma unroll 4
        for (int i = i0; i < i0 + 256; i += 4) {
            float4 v = *(const float4*)&s_h[i];
            f2 = fmaf(v.x, W2f[(i + 0) * DIM + col], f2);
            f2 = fmaf(v.y, W2f[(i + 1) * DIM + col], f2);
            f2 = fmaf(v.z, W2f[(i + 2) * DIM + col], f2);
            f2 = fmaf(v.w, W2f[(i + 3) * DIM + col], f2);
        }
    }
    s_part[tid] = f2;
    __syncthreads();                                             // B12
    float ffn = 0.0f;
    if (tid < 128) {
        ffn = s_part[tid] + s_part[tid + 128];
        float sum = ffn;
        for (int off = 32; off; off >>= 1) sum += __shfl_xor(sum, off, 64);
        if (lane == 0) s_red[wv] = sum;
    }
    __syncthreads();                                             // B13
    mu = (s_red[0] + s_red[1]) * (1.0f / 128.0f);
    xc = ffn - mu;
    if (tid < 128) {
        float q2 = xc * xc;
        for (int off = 32; off; off >>= 1) q2 += __shfl_xor(q2, off, 64);
        if (lane == 0) s_red[2 + wv] = q2;
    }
    __syncthreads();                                             // B14
    var = (s_red[2] + s_red[3]) * (1.0f / 128.0f);
    if (tid < 128) {
        float rs2 = 1.0f / sqrtf(var + LN_EPS);
        float ln2 = fmaf(xc * rs2, Pf[384 + tid], Pf[512 + tid]);  // n2w, n2b
        cf_out[(size_t)m * DIM + tid] = cf1 + ln2;
    }
}

// =================== kernel: wave-per-point KNN select + upsample -> up (stored in d_out) ===================
#define CSWAP(a, b) { if ((b) < (a)) { u64 t_ = (a); (a) = (b); (b) = t_; } }

__global__ __launch_bounds__(256) void knn_select(
    const float4* __restrict__ pnt4,
    const float4* __restrict__ cent4,
    const float* __restrict__ cf,
    float* __restrict__ upg,          // = d_out, N x 128 f32
    int N, int M) {

    int lane = threadIdx.x & 63;
    int wv   = threadIdx.x >> 6;
    int p = blockIdx.x * 4 + wv;
    bool own = (p < N);

    float4 pp = make_float4(0.f, 0.f, 0.f, 0.f);
    if (own) pp = pnt4[p];          // own is wave-uniform

    // ---- fast scan: per-lane top-3 ----
    u64 b0 = ~0ULL, b1 = ~0ULL, b2 = ~0ULL;
    for (int j = lane; j < M; j += 64) {
        float4 cc = cent4[j];
        float dist = dist32(cc.x, cc.y, cc.z, cc.w, pp.x, pp.y, pp.z, pp.w);
        u64 key = ((u64)__float_as_uint(dist) << 32) | (unsigned)j;
        if (key < b2) {
            b2 = key;
            CSWAP(b1, b2); CSWAP(b0, b1);
        }
    }

    // ---- ascending merge from top-3 heads ----
    int   ptr = 0;
    u64   cur = b0;
    float wsum = 0.0f;
    int   ki[8];
    float w8[8];
#pragma unroll
    for (int e = 0; e < 8; ++e) {
        u64 v = cur;
        for (int off = 32; off; off >>= 1) {
            u64 o = __shfl_down(v, off, 64);
            v = (o < v) ? o : v;
        }
        u64 gm = __shfl(v, 0, 64);                 // global min, broadcast
        float d = __uint_as_float((unsigned)(gm >> 32));
        int ci = (int)(unsigned)(gm & 0xFFFFFFFFULL);
        ci = (ci >= 0 && ci < M) ? ci : 0;
        float t = __fadd_rn(d, 1e-6f);
        float w = 1.0f / __fmul_rn(t, t);
        wsum += w;                                 // ascending-order sum (bit-exact)
        ki[e] = ci;
        w8[e] = w;
        if (cur == gm) {                           // unique owner advances
            ptr++;
            cur = (ptr == 1) ? b1 : (ptr == 2) ? b2 : ~0ULL;
        }
    }

    // ---- exactness check: any lane exhausted its 3 -> full 8-deep rescan ----
    if (__ballot(ptr >= 3) != 0ULL) {
        u64 f0 = ~0ULL, f1_ = ~0ULL, f2_ = ~0ULL, f3 = ~0ULL,
            f4 = ~0ULL, f5 = ~0ULL, f6 = ~0ULL, f7 = ~0ULL;
        for (int j = lane; j < M; j += 64) {
            float4 cc = cent4[j];
            float dist = dist32(cc.x, cc.y, cc.z, cc.w, pp.x, pp.y, pp.z, pp.w);
            u64 key = ((u64)__float_as_uint(dist) << 32) | (unsigned)j;
            if (key < f7) {
                f7 = key;
                CSWAP(f6, f7); CSWAP(f5, f6); CSWAP(f4, f5); CSWAP(f3, f4);
                CSWAP(f2_, f3); CSWAP(f1_, f2_); CSWAP(f0, f1_);
            }
        }
        int ptr2 = 0;
        u64 cur2 = f0;
        wsum = 0.0f;
#pragma unroll
        for (int e = 0; e < 8; ++e) {
            u64 v = cur2;
            for (int off = 32; off; off >>= 1) {
                u64 o = __shfl_down(v, off, 64);
                v = (o < v) ? o : v;
            }
            u64 gm = __shfl(v, 0, 64);
            float d = __uint_as_float((unsigned)(gm >> 32));
            int ci = (int)(unsigned)(gm & 0xFFFFFFFFULL);
            ci = (ci >= 0 && ci < M) ? ci : 0;
            float t = __fadd_rn(d, 1e-6f);
            float w = 1.0f / __fmul_rn(t, t);
            wsum += w;
            ki[e] = ci;
            w8[e] = w;
            if (cur2 == gm) {
                ptr2++;
                cur2 = (ptr2 == 1) ? f1_ : (ptr2 == 2) ? f2_ : (ptr2 == 3) ? f3 :
                       (ptr2 == 4) ? f4 : (ptr2 == 5) ? f5 : (ptr2 == 6) ? f6 :
                       (ptr2 == 7) ? f7 : ~0ULL;
            }
        }
    }

    float inv = 1.0f / wsum;
#pragma unroll
    for (int e = 0; e < 8; ++e) w8[e] *= inv;

    // ---- upsample: lane owns cols lane and lane+64 (k ascending, bit-exact) ----
    int c0 = lane, c1 = lane + 64;
    float up0 = 0.0f, up1 = 0.0f;
#pragma unroll
    for (int k = 0; k < 8; ++k) {
        const float* row = cf + (size_t)ki[k] * DIM;
        up0 = fmaf(w8[k], row[c0], up0);
        up1 = fmaf(w8[k], row[c1], up1);
    }

    if (own) {
        upg[(size_t)p * DIM + c0] = up0;
        upg[(size_t)p * DIM + c1] = up1;
    }
}

// =================== kernel: tiled Wp GEMM + epilogue, in place over d_out ===================
__global__ __launch_bounds__(256) void wp_out(
    const float* __restrict__ Wf,
    const void* __restrict__ feats,
    const int* __restrict__ fl,
    float* __restrict__ out,          // holds up on entry, final output on exit
    int N) {

    const float* Wpf = Wf + 196608;
    const float* bpf = Wf + 212992 + 1280;

    __shared__ __align__(16) float s_up[PB][132];   // +4 pad: 16B-aligned rows, bank spread

    int tid = threadIdx.x;
    int p0 = blockIdx.x * PB;

    // stage up tile (32 pts x 128), zero-fill past N
    for (int f = tid; f < PB * 32; f += 256) {
        int p = f >> 5, i4 = (f & 31) << 2;
        float4 v = make_float4(0.f, 0.f, 0.f, 0.f);
        if (p0 + p < N) v = *(const float4*)&out[(size_t)(p0 + p) * DIM + i4];
        *(float4*)&s_up[p][i4] = v;
    }
    __syncthreads();

    // thread = 4 cols x 4 pts register tile
    int cq = tid & 31, pq = tid >> 5;
    int c0 = cq << 2;
    int pA = pq << 2;

    float a00 = 0.f, a01 = 0.f, a02 = 0.f, a03 = 0.f;
    float a10 = 0.f, a11 = 0.f, a12 = 0.f, a13 = 0.f;
    float a20 = 0.f, a21 = 0.f, a22 = 0.f, a23 = 0.f;
    float a30 = 0.f, a31 = 0.f, a32 = 0.f, a33 = 0.f;

#pragma unroll 4
    for (int i = 0; i < DIM; ++i) {
        float4 w = *(const float4*)&Wpf[(size_t)i * DIM + c0];
        float u0 = s_up[pA + 0][i];
        float u1 = s_up[pA + 1][i];
        float u2 = s_up[pA + 2][i];
        float u3 = s_up[pA + 3][i];
        a00 = fmaf(u0, w.x, a00); a01 = fmaf(u0, w.y, a01);
        a02 = fmaf(u0, w.z, a02); a03 = fmaf(u0, w.w, a03);
        a10 = fmaf(u1, w.x, a10); a11 = fmaf(u1, w.y, a11);
        a12 = fmaf(u1, w.z, a12); a13 = fmaf(u1, w.w, a13);
        a20 = fmaf(u2, w.x, a20); a21 = fmaf(u2, w.y, a21);
        a22 = fmaf(u2, w.z, a22); a23 = fmaf(u2, w.w, a23);
        a30 = fmaf(u3, w.x, a30); a31 = fmaf(u3, w.y, a31);
        a32 = fmaf(u3, w.z, a32); a33 = fmaf(u3, w.w, a33);
    }

    int f1v = fl[1];
    float4 bp4 = make_float4(bpf[c0 + 0], bpf[c0 + 1], bpf[c0 + 2], bpf[c0 + 3]);

    float accs[4][4] = {{a00, a01, a02, a03}, {a10, a11, a12, a13},
                        {a20, a21, a22, a23}, {a30, a31, a32, a33}};
#pragma unroll
    for (int a = 0; a < 4; ++a) {
        int p = p0 + pA + a;
        if (p < N) {
            float4 u = *(const float4*)&s_up[pA + a][c0];
            float4 o;
            o.x = ldf(feats, f1v, (size_t)p * DIM + c0 + 0) + u.x + fmaxf(bp4.x + accs[a][0], 0.0f);
            o.y = ldf(feats, f1v, (size_t)p * DIM + c0 + 1) + u.y + fmaxf(bp4.y + accs[a][1], 0.0f);
            o.z = ldf(feats, f1v, (size_t)p * DIM + c0 + 2) + u.z + fmaxf(bp4.z + accs[a][2], 0.0f);
            o.w = ldf(feats, f1v, (size_t)p * DIM + c0 + 3) + u.w + fmaxf(bp4.w + accs[a][3], 0.0f);
            *(float4*)&out[(size_t)p * DIM + c0] = o;
        }
    }
}

extern "C" void kernel_launch(void* const* d_in, const int* in_sizes, int n_in,
                              void* d_out, int out_size, void* d_ws, size_t ws_size,
                              hipStream_t stream) {
    int N = in_sizes[0] / 3;
    int M = in_sizes[17];

    Ptrs P;
    for (int j = 0; j < 18; ++j) { P.p[j] = d_in[j]; P.sz[j] = in_sizes[j]; }

    size_t off = 0;
    auto alloc = [&](size_t bytes) -> void* {
        off = (off + 255) & ~(size_t)255;
        void* p = (void*)((char*)d_ws + off);
        off += bytes;
        return p;
    };
    int*    fl    = (int*)alloc(32 * 4);
    float*  Wf    = (float*)alloc((size_t)WTOT * 4);          // 858 KB
    float4* pnt4  = (float4*)alloc((size_t)N * 16);           // 800 KB
    float4* cent4 = (float4*)alloc((size_t)M * 16);           //  40 KB
    float*  cfbuf = (float*)alloc((size_t)M * DIM * 4);       // 1.28 MB
    int*    nbr   = (int*)alloc((size_t)M * KMAX * 4);        // 320 KB (total ~3.3 MB)

    probe_dtypes<<<1, 32, 0, stream>>>(P, fl);
    conv_params<<<(WTOT + 255) / 256, 256, 0, stream>>>(P, fl, Wf);
    prep_pts<<<(N + 255) / 256, 256, 0, stream>>>(d_in[0], fl, pnt4, N);
    prep_ctrs<<<(M + 255) / 256, 256, 0, stream>>>(d_in[17], fl, pnt4, cent4, M, N);
    ball_scan<<<M, 256, 0, stream>>>(pnt4, cent4, N, nbr);
    attn_ffn<<<M, 256, 0, stream>>>(nbr, d_in[1], d_in[17], fl, Wf, cfbuf, N);
    knn_select<<<(N + 3) / 4, 256, 0, stream>>>(pnt4, cent4, cfbuf, (float*)d_out, N, M);
    wp_out<<<(N + PB - 1) / PB, 256, 0, stream>>>(Wf, d_in[1], fl, (float*)d_out, N);
}

// Round 3
// 581.587 us; speedup vs baseline: 1.1051x; 1.0743x over previous
//
#include <hip/hip_runtime.h>
#include <hip/hip_bf16.h>
#include <stdint.h>

#define DIM    128
#define KMAX   32
#define LN_EPS 1e-5f
#define ATT_SCALE 0.17677669529663687f   // 32^-0.5
#define CAND   2048
#define WTOT   214400                    // 212992 weight f32 + 1408 param f32
#define PB     32                        // points per block in wp_out
#define NSTR   36                        // nft row stride (16B-aligned quads)
#define KSTR   132                       // s_kv row stride (16B-aligned quads)

typedef unsigned long long u64;
static __device__ __forceinline__ float bf2f(__hip_bfloat16 x) { return __bfloat162float(x); }

// ---- bit-exact replica of the np-fp32 distance pipeline (DO NOT TOUCH: passing) ----
static __device__ __forceinline__ float norm32(float x, float y, float z) {
    return __fadd_rn(__fadd_rn(__fmul_rn(x, x), __fmul_rn(y, y)), __fmul_rn(z, z));
}
static __device__ __forceinline__ float d2_32(float cx, float cy, float cz, float cw,
                                              float px, float py, float pz, float pw) {
    float dot = __fmaf_rn(cz, pz, __fmaf_rn(cy, py, __fmul_rn(cx, px)));
    return __fsub_rn(__fadd_rn(cw, pw), __fmul_rn(2.0f, dot));
}
static __device__ __forceinline__ float d2_to_dist(float d2) {
    d2 = fmaxf(d2, 0.0f);
    return (d2 > 0.0f) ? __fsqrt_rn(d2) : 0.0f;
}
static __device__ __forceinline__ float dist32(float cx, float cy, float cz, float cw,
                                               float px, float py, float pz, float pw) {
    return d2_to_dist(d2_32(cx, cy, cz, cw, px, py, pz, pw));
}

static __device__ __forceinline__ float ldf(const void* p, int f32, size_t i) {
    return f32 ? ((const float*)p)[i] : bf2f(((const __hip_bfloat16*)p)[i]);
}
static __device__ __forceinline__ int ldidx(const void* p, int i64, int m) {
    return i64 ? ((const int*)p)[2 * m] : ((const int*)p)[m];
}

struct Ptrs { const void* p[18]; int sz[18]; };

// ---------- probe: classify each input's dtype on-device (unchanged, passing) ----------
__global__ void probe_dtypes(Ptrs P, int* __restrict__ fl) {
    int j = threadIdx.x;
    if (j >= 18) return;
    const void* x = P.p[j];
    int sz = P.sz[j];
    int flag = 0;
    if (j == 17) {
        const int* ip = (const int*)x;
        int odd_zero = 1, even_nz = 0;
        for (int k = 0; k < 8 && 2 * k + 1 < sz * 2; ++k) {
            if (ip[2 * k + 1] != 0) odd_zero = 0;
            if (ip[2 * k] != 0) even_nz = 1;
        }
        flag = (odd_zero && even_nz) ? 1 : 0;
    } else {
        const __hip_bfloat16* hp = (const __hip_bfloat16*)x;
        int n = sz < 256 ? sz : 256;
        for (int i = 0; i < n; ++i) {
            float w = bf2f(hp[i]);
            if (w != w || fabsf(w) > 1000.0f) { flag = 1; break; }
        }
        if ((j == 7 || j == 9) && bf2f(hp[0]) == 0.0f) flag = 1;
    }
    fl[j] = flag;
}

// ---------- convert weights+params -> canonical fp32 (unchanged) ----------
__global__ __launch_bounds__(256) void conv_params(Ptrs P, const int* __restrict__ fl,
                                                   float* __restrict__ Wf) {
    int i = blockIdx.x * 256 + threadIdx.x;
    if (i >= WTOT) return;
    int j, off;
    if      (i < 16384)  { j = 2;  off = i; }
    else if (i < 32768)  { j = 3;  off = i - 16384; }
    else if (i < 49152)  { j = 4;  off = i - 32768; }
    else if (i < 65536)  { j = 5;  off = i - 49152; }
    else if (i < 131072) { j = 11; off = i - 65536; }
    else if (i < 196608) { j = 13; off = i - 131072; }
    else if (i < 212992) { j = 15; off = i - 196608; }
    else if (i < 213120) { j = 6;  off = i - 212992; }
    else if (i < 213248) { j = 7;  off = i - 213120; }
    else if (i < 213376) { j = 8;  off = i - 213248; }
    else if (i < 213504) { j = 9;  off = i - 213376; }
    else if (i < 213632) { j = 10; off = i - 213504; }
    else if (i < 214144) { j = 12; off = i - 213632; }
    else if (i < 214272) { j = 14; off = i - 214144; }
    else                 { j = 16; off = i - 214272; }
    Wf[i] = ldf(P.p[j], fl[j], off);
}

__global__ void prep_pts(const void* __restrict__ xyz, const int* __restrict__ fl,
                         float4* __restrict__ pnt4, int N) {
    int i = blockIdx.x * 256 + threadIdx.x;
    if (i < N) {
        int f = fl[0];
        float x = ldf(xyz, f, 3 * i + 0), y = ldf(xyz, f, 3 * i + 1), z = ldf(xyz, f, 3 * i + 2);
        pnt4[i] = make_float4(x, y, z, norm32(x, y, z));
    }
}

__global__ void prep_ctrs(const void* __restrict__ idxc, const int* __restrict__ fl,
                          const float4* __restrict__ pnt4, float4* __restrict__ cent4,
                          int M, int N) {
    int m = blockIdx.x * 256 + threadIdx.x;
    if (m < M) {
        int c = ldidx(idxc, fl[17], m);
        c = (c >= 0 && c < N) ? c : 0;
        cent4[m] = pnt4[c];
    }
}

// =================== kernel: ball query scan + top-32 select -> nbr_g (unchanged) ===================
__global__ __launch_bounds__(256) void ball_scan(
    const float4* __restrict__ pnt4,
    const float4* __restrict__ cent4,
    int N, int* __restrict__ nbr_g) {

    __shared__ u64 key[CAND];        // 16 KB
    __shared__ int s_cnt, s_ni[KMAX];

    int m = blockIdx.x, tid = threadIdx.x;
    float4 cc4 = cent4[m];

    if (tid == 0) s_cnt = 0;
    if (tid < KMAX) s_ni[tid] = -1;
    __syncthreads();

    for (int i = tid; i < N; i += 256) {
        float4 p = pnt4[i];
        float d2 = d2_32(cc4.x, cc4.y, cc4.z, cc4.w, p.x, p.y, p.z, p.w);
        if (d2 < 0.0901f) {
            float dist = d2_to_dist(d2);
            if (dist < 0.3f) {
                int pos = atomicAdd(&s_cnt, 1);
                if (pos < CAND)
                    key[pos] = ((u64)__float_as_uint(dist) << 32) | (unsigned)i;
            }
        }
    }
    __syncthreads();
    int cnt = min(s_cnt, CAND);

    for (int i = tid; i < cnt; i += 256) {
        u64 ki = key[i];
        int r = 0;
        for (int j = 0; j < cnt; ++j) r += (key[j] < ki) ? 1 : 0;
        if (r < KMAX) s_ni[r] = (int)(unsigned)(ki & 0xFFFFFFFFULL);
    }
    __syncthreads();
    if (tid < KMAX) nbr_g[m * KMAX + tid] = s_ni[tid];
}

// =================== kernel: attention + FFN -> cf ===================
// v3: K/V GEMM retiled as register outer-product. Thread (kq,cq) owns a 4x4 tile of BOTH
// K and V: per i-step 1 aligned ds_read_b128 of nft[i][4kq..+3] + 2 float4 weight loads
// + 32 fma, vs the old 8 misaligned LDS float4 reads + 1 scalar weight load + 32 fma.
// LDS-pipe instruction count in the dominant loop drops ~8x. Per-(kk,col) fma chain is
// i=0..127 ascending, identical operands -> bit-exact vs v2. nft stride 33->36 and s_kv
// stride 130->132 for 16B alignment (layout only). Softmax/PV/Wo/LN/FFN unchanged.
#define NFT(cc, kk) R[(cc) * NSTR + (kk)]
#define SKV(kk, col) R[(kk) * KSTR + (col)]

__global__ __launch_bounds__(256) void attn_ffn(
    const int* __restrict__ nbr_g,
    const void* __restrict__ feats,
    const void* __restrict__ idxc,
    const int* __restrict__ fl,
    const float* __restrict__ Wf,
    float* __restrict__ cf_out, int N) {

    const float* Wqf = Wf;
    const float* Wkf = Wf + 16384;
    const float* Wvf = Wf + 32768;
    const float* Wof = Wf + 49152;
    const float* W1f = Wf + 65536;
    const float* W2f = Wf + 131072;
    const float* Pf  = Wf + 212992;

    __shared__ __align__(16) float R[128 * NSTR];   // 18.4KB: nft[128][36] | s_kv[32][132] | s_h+s_part
    __shared__ int   s_ni[KMAX];
    __shared__ __align__(16) float s_cf[DIM], s_q[DIM], s_attn[DIM], s_ao[DIM], s_x[DIM];
    __shared__ float s_red[4];

    int m = blockIdx.x, tid = threadIdx.x;
    int lane = tid & 63, wv = tid >> 6;
    int f1 = fl[1];
    int c = ldidx(idxc, fl[17], m);
    c = (c >= 0 && c < N) ? c : 0;

    if (tid < KMAX) s_ni[tid] = nbr_g[m * KMAX + tid];
    if (tid < 128) s_cf[tid] = ldf(feats, f1, (size_t)c * DIM + tid);
    __syncthreads();                                             // B1
    for (int t = tid; t < KMAX * DIM; t += 256) {
        int kk = t >> 7, cc = t & 127;
        int idx = s_ni[kk];
        float v = (idx >= 0 && idx < N) ? ldf(feats, f1, (size_t)idx * DIM + cc) : 0.0f;
        NFT(cc, kk) = v;
    }
    __syncthreads();                                             // B2

    if (tid < 128) {
        float acc = 0.0f;
#pragma unroll 4
        for (int i = 0; i < DIM; i += 4) {
            float4 a = *(const float4*)&s_cf[i];
            acc = fmaf(a.x, Wqf[(i + 0) * DIM + tid], acc);
            acc = fmaf(a.y, Wqf[(i + 1) * DIM + tid], acc);
            acc = fmaf(a.z, Wqf[(i + 2) * DIM + tid], acc);
            acc = fmaf(a.w, Wqf[(i + 3) * DIM + tid], acc);
        }
        s_q[tid] = acc;
    }

    // ---- K/V GEMM: register outer-product, thread = 4 k-rows x 4 cols, both mats ----
    int kq = tid >> 5, cq = tid & 31;
    int k0 = kq * 4, c0 = cq * 4;
    float ka[4][4], va[4][4];
#pragma unroll
    for (int j = 0; j < 4; ++j)
#pragma unroll
        for (int cc2 = 0; cc2 < 4; ++cc2) { ka[j][cc2] = 0.0f; va[j][cc2] = 0.0f; }

#pragma unroll 2
    for (int i = 0; i < DIM; ++i) {
        float4 n  = *(const float4*)&NFT(i, k0);
        float4 wk = *(const float4*)&Wkf[i * DIM + c0];
        float4 wv4 = *(const float4*)&Wvf[i * DIM + c0];
#pragma unroll
        for (int j = 0; j < 4; ++j) {
            float nj = (&n.x)[j];
            ka[j][0] = fmaf(nj, wk.x, ka[j][0]);
            ka[j][1] = fmaf(nj, wk.y, ka[j][1]);
            ka[j][2] = fmaf(nj, wk.z, ka[j][2]);
            ka[j][3] = fmaf(nj, wk.w, ka[j][3]);
            va[j][0] = fmaf(nj, wv4.x, va[j][0]);
            va[j][1] = fmaf(nj, wv4.y, va[j][1]);
            va[j][2] = fmaf(nj, wv4.z, va[j][2]);
            va[j][3] = fmaf(nj, wv4.w, va[j][3]);
        }
    }
    __syncthreads();                                             // B3: nft reads done, R reusable
#pragma unroll
    for (int j = 0; j < 4; ++j)
        *(float4*)&SKV(k0 + j, c0) = make_float4(ka[j][0], ka[j][1], ka[j][2], ka[j][3]);
    __syncthreads();                                             // B4

    if (tid < 128) {
        int h = tid >> 5, kk = tid & 31;
        float s = 0.0f;
#pragma unroll
        for (int d = 0; d < 32; ++d)
            s = fmaf(s_q[h * 32 + d], SKV(kk, h * 32 + d), s);
        s *= ATT_SCALE;
        if (s_ni[kk] < 0) s = -1e9f;
        // per-head softmax via 32-lane shuffle reduce (head = 32 contiguous lanes)
        float mx = s;
        for (int off = 16; off; off >>= 1) mx = fmaxf(mx, __shfl_xor(mx, off, 32));
        float e = expf(s - mx);
        float sm = e;
        for (int off = 16; off; off >>= 1) sm += __shfl_xor(sm, off, 32);
        sm = (sm > 0.0f) ? sm : 1.0f;
        s_attn[tid] = e / sm;
    }
    __syncthreads();                                             // B5: attn ready, K reads done
#pragma unroll
    for (int j = 0; j < 4; ++j)
        *(float4*)&SKV(k0 + j, c0) = make_float4(va[j][0], va[j][1], va[j][2], va[j][3]);
    __syncthreads();                                             // B6

    if (tid < 128) {
        int h = tid >> 5, d = tid & 31;
        float o = 0.0f;
#pragma unroll
        for (int kk = 0; kk < KMAX; ++kk)
            o = fmaf(s_attn[h * 32 + kk], SKV(kk, h * 32 + d), o);
        s_ao[d * 4 + h] = o;
    }
    __syncthreads();                                             // B7

    float upd = 0.0f;
    if (tid < 128) {
        upd = Pf[0 + tid];  // bo
#pragma unroll 4
        for (int i = 0; i < DIM; i += 4) {
            float4 a = *(const float4*)&s_ao[i];
            upd = fmaf(a.x, Wof[(i + 0) * DIM + tid], upd);
            upd = fmaf(a.y, Wof[(i + 1) * DIM + tid], upd);
            upd = fmaf(a.z, Wof[(i + 2) * DIM + tid], upd);
            upd = fmaf(a.w, Wof[(i + 3) * DIM + tid], upd);
        }
        float sum = upd;
        for (int off = 32; off; off >>= 1) sum += __shfl_xor(sum, off, 64);
        if (lane == 0) s_red[wv] = sum;
    }
    __syncthreads();                                             // B8
    float mu = (s_red[0] + s_red[1]) * (1.0f / 128.0f);
    float xc = upd - mu;
    if (tid < 128) {
        float q2 = xc * xc;
        for (int off = 32; off; off >>= 1) q2 += __shfl_xor(q2, off, 64);
        if (lane == 0) s_red[2 + wv] = q2;
    }
    __syncthreads();                                             // B9
    float var = (s_red[2] + s_red[3]) * (1.0f / 128.0f);
    float cf1 = 0.0f;
    if (tid < 128) {
        float rs = 1.0f / sqrtf(var + LN_EPS);
        float ln1 = fmaf(xc * rs, Pf[128 + tid], Pf[256 + tid]);  // n1w, n1b
        cf1 = s_cf[tid] + ln1;
        s_x[tid] = cf1;
    }
    __syncthreads();                                             // B10

    float* s_h = R;              // R[0..512): FFN hidden
    float* s_part = R + 512;     // R[512..768): W2 partials
#pragma unroll
    for (int jj = 0; jj < 2; ++jj) {
        int j = jj * 256 + tid;
        float a = Pf[640 + j];  // b1
#pragma unroll 4
        for (int i = 0; i < DIM; i += 4) {
            float4 v = *(const float4*)&s_x[i];
            a = fmaf(v.x, W1f[(i + 0) * 512 + j], a);
            a = fmaf(v.y, W1f[(i + 1) * 512 + j], a);
            a = fmaf(v.z, W1f[(i + 2) * 512 + j], a);
            a = fmaf(v.w, W1f[(i + 3) * 512 + j], a);
        }
        s_h[j] = fmaxf(a, 0.0f);
    }
    __syncthreads();                                             // B11

    int col = tid & 127;
    int half = tid >> 7;
    float f2 = (half == 0) ? Pf[1152 + col] : 0.0f;  // b2
    {
        int i0 = half * 256;
#pragma unroll 4
        for (int i = i0; i < i0 + 256; i += 4) {
            float4 v = *(const float4*)&s_h[i];
            f2 = fmaf(v.x, W2f[(i + 0) * DIM + col], f2);
            f2 = fmaf(v.y, W2f[(i + 1) * DIM + col], f2);
            f2 = fmaf(v.z, W2f[(i + 2) * DIM + col], f2);
            f2 = fmaf(v.w, W2f[(i + 3) * DIM + col], f2);
        }
    }
    float* s_part2 = s_part;
    s_part2[tid] = f2;
    __syncthreads();                                             // B12
    float ffn = 0.0f;
    if (tid < 128) {
        ffn = s_part2[tid] + s_part2[tid + 128];
        float sum = ffn;
        for (int off = 32; off; off >>= 1) sum += __shfl_xor(sum, off, 64);
        if (lane == 0) s_red[wv] = sum;
    }
    __syncthreads();                                             // B13
    mu = (s_red[0] + s_red[1]) * (1.0f / 128.0f);
    xc = ffn - mu;
    if (tid < 128) {
        float q2 = xc * xc;
        for (int off = 32; off; off >>= 1) q2 += __shfl_xor(q2, off, 64);
        if (lane == 0) s_red[2 + wv] = q2;
    }
    __syncthreads();                                             // B14
    var = (s_red[2] + s_red[3]) * (1.0f / 128.0f);
    if (tid < 128) {
        float rs2 = 1.0f / sqrtf(var + LN_EPS);
        float ln2 = fmaf(xc * rs2, Pf[384 + tid], Pf[512 + tid]);  // n2w, n2b
        cf_out[(size_t)m * DIM + tid] = cf1 + ln2;
    }
}

// =================== kernel: wave-per-point KNN select + upsample -> up (stored in d_out) ===================
#define CSWAP(a, b) { if ((b) < (a)) { u64 t_ = (a); (a) = (b); (b) = t_; } }

__global__ __launch_bounds__(256) void knn_select(
    const float4* __restrict__ pnt4,
    const float4* __restrict__ cent4,
    const float* __restrict__ cf,
    float* __restrict__ upg,          // = d_out, N x 128 f32
    int N, int M) {

    int lane = threadIdx.x & 63;
    int wv   = threadIdx.x >> 6;
    int p = blockIdx.x * 4 + wv;
    bool own = (p < N);

    float4 pp = make_float4(0.f, 0.f, 0.f, 0.f);
    if (own) pp = pnt4[p];          // own is wave-uniform

    // ---- fast scan: per-lane top-3 ----
    u64 b0 = ~0ULL, b1 = ~0ULL, b2 = ~0ULL;
    for (int j = lane; j < M; j += 64) {
        float4 cc = cent4[j];
        float dist = dist32(cc.x, cc.y, cc.z, cc.w, pp.x, pp.y, pp.z, pp.w);
        u64 key = ((u64)__float_as_uint(dist) << 32) | (unsigned)j;
        if (key < b2) {
            b2 = key;
            CSWAP(b1, b2); CSWAP(b0, b1);
        }
    }

    // ---- ascending merge from top-3 heads ----
    int   ptr = 0;
    u64   cur = b0;
    float wsum = 0.0f;
    int   ki[8];
    float w8[8];
#pragma unroll
    for (int e = 0; e < 8; ++e) {
        u64 v = cur;
        for (int off = 32; off; off >>= 1) {
            u64 o = __shfl_down(v, off, 64);
            v = (o < v) ? o : v;
        }
        u64 gm = __shfl(v, 0, 64);                 // global min, broadcast
        float d = __uint_as_float((unsigned)(gm >> 32));
        int ci = (int)(unsigned)(gm & 0xFFFFFFFFULL);
        ci = (ci >= 0 && ci < M) ? ci : 0;
        float t = __fadd_rn(d, 1e-6f);
        float w = 1.0f / __fmul_rn(t, t);
        wsum += w;                                 // ascending-order sum (bit-exact)
        ki[e] = ci;
        w8[e] = w;
        if (cur == gm) {                           // unique owner advances
            ptr++;
            cur = (ptr == 1) ? b1 : (ptr == 2) ? b2 : ~0ULL;
        }
    }

    // ---- exactness check: any lane exhausted its 3 -> full 8-deep rescan ----
    if (__ballot(ptr >= 3) != 0ULL) {
        u64 f0 = ~0ULL, f1_ = ~0ULL, f2_ = ~0ULL, f3 = ~0ULL,
            f4 = ~0ULL, f5 = ~0ULL, f6 = ~0ULL, f7 = ~0ULL;
        for (int j = lane; j < M; j += 64) {
            float4 cc = cent4[j];
            float dist = dist32(cc.x, cc.y, cc.z, cc.w, pp.x, pp.y, pp.z, pp.w);
            u64 key = ((u64)__float_as_uint(dist) << 32) | (unsigned)j;
            if (key < f7) {
                f7 = key;
                CSWAP(f6, f7); CSWAP(f5, f6); CSWAP(f4, f5); CSWAP(f3, f4);
                CSWAP(f2_, f3); CSWAP(f1_, f2_); CSWAP(f0, f1_);
            }
        }
        int ptr2 = 0;
        u64 cur2 = f0;
        wsum = 0.0f;
#pragma unroll
        for (int e = 0; e < 8; ++e) {
            u64 v = cur2;
            for (int off = 32; off; off >>= 1) {
                u64 o = __shfl_down(v, off, 64);
                v = (o < v) ? o : v;
            }
            u64 gm = __shfl(v, 0, 64);
            float d = __uint_as_float((unsigned)(gm >> 32));
            int ci = (int)(unsigned)(gm & 0xFFFFFFFFULL);
            ci = (ci >= 0 && ci < M) ? ci : 0;
            float t = __fadd_rn(d, 1e-6f);
            float w = 1.0f / __fmul_rn(t, t);
            wsum += w;
            ki[e] = ci;
            w8[e] = w;
            if (cur2 == gm) {
                ptr2++;
                cur2 = (ptr2 == 1) ? f1_ : (ptr2 == 2) ? f2_ : (ptr2 == 3) ? f3 :
                       (ptr2 == 4) ? f4 : (ptr2 == 5) ? f5 : (ptr2 == 6) ? f6 :
                       (ptr2 == 7) ? f7 : ~0ULL;
            }
        }
    }

    float inv = 1.0f / wsum;
#pragma unroll
    for (int e = 0; e < 8; ++e) w8[e] *= inv;

    // ---- upsample: lane owns cols lane and lane+64 (k ascending, bit-exact) ----
    int c0 = lane, c1 = lane + 64;
    float up0 = 0.0f, up1 = 0.0f;
#pragma unroll
    for (int k = 0; k < 8; ++k) {
        const float* row = cf + (size_t)ki[k] * DIM;
        up0 = fmaf(w8[k], row[c0], up0);
        up1 = fmaf(w8[k], row[c1], up1);
    }

    if (own) {
        upg[(size_t)p * DIM + c0] = up0;
        upg[(size_t)p * DIM + c1] = up1;
    }
}

// =================== kernel: tiled Wp GEMM + epilogue, in place over d_out ===================
__global__ __launch_bounds__(256) void wp_out(
    const float* __restrict__ Wf,
    const void* __restrict__ feats,
    const int* __restrict__ fl,
    float* __restrict__ out,          // holds up on entry, final output on exit
    int N) {

    const float* Wpf = Wf + 196608;
    const float* bpf = Wf + 212992 + 1280;

    __shared__ __align__(16) float s_up[PB][132];   // +4 pad: 16B-aligned rows, bank spread

    int tid = threadIdx.x;
    int p0 = blockIdx.x * PB;

    // stage up tile (32 pts x 128), zero-fill past N
    for (int f = tid; f < PB * 32; f += 256) {
        int p = f >> 5, i4 = (f & 31) << 2;
        float4 v = make_float4(0.f, 0.f, 0.f, 0.f);
        if (p0 + p < N) v = *(const float4*)&out[(size_t)(p0 + p) * DIM + i4];
        *(float4*)&s_up[p][i4] = v;
    }
    __syncthreads();

    // thread = 4 cols x 4 pts register tile
    int cq = tid & 31, pq = tid >> 5;
    int c0 = cq << 2;
    int pA = pq << 2;

    float a00 = 0.f, a01 = 0.f, a02 = 0.f, a03 = 0.f;
    float a10 = 0.f, a11 = 0.f, a12 = 0.f, a13 = 0.f;
    float a20 = 0.f, a21 = 0.f, a22 = 0.f, a23 = 0.f;
    float a30 = 0.f, a31 = 0.f, a32 = 0.f, a33 = 0.f;

#pragma unroll 4
    for (int i = 0; i < DIM; ++i) {
        float4 w = *(const float4*)&Wpf[(size_t)i * DIM + c0];
        float u0 = s_up[pA + 0][i];
        float u1 = s_up[pA + 1][i];
        float u2 = s_up[pA + 2][i];
        float u3 = s_up[pA + 3][i];
        a00 = fmaf(u0, w.x, a00); a01 = fmaf(u0, w.y, a01);
        a02 = fmaf(u0, w.z, a02); a03 = fmaf(u0, w.w, a03);
        a10 = fmaf(u1, w.x, a10); a11 = fmaf(u1, w.y, a11);
        a12 = fmaf(u1, w.z, a12); a13 = fmaf(u1, w.w, a13);
        a20 = fmaf(u2, w.x, a20); a21 = fmaf(u2, w.y, a21);
        a22 = fmaf(u2, w.z, a22); a23 = fmaf(u2, w.w, a23);
        a30 = fmaf(u3, w.x, a30); a31 = fmaf(u3, w.y, a31);
        a32 = fmaf(u3, w.z, a32); a33 = fmaf(u3, w.w, a33);
    }

    int f1v = fl[1];
    float4 bp4 = make_float4(bpf[c0 + 0], bpf[c0 + 1], bpf[c0 + 2], bpf[c0 + 3]);

    float accs[4][4] = {{a00, a01, a02, a03}, {a10, a11, a12, a13},
                        {a20, a21, a22, a23}, {a30, a31, a32, a33}};
#pragma unroll
    for (int a = 0; a < 4; ++a) {
        int p = p0 + pA + a;
        if (p < N) {
            float4 u = *(const float4*)&s_up[pA + a][c0];
            float4 o;
            o.x = ldf(feats, f1v, (size_t)p * DIM + c0 + 0) + u.x + fmaxf(bp4.x + accs[a][0], 0.0f);
            o.y = ldf(feats, f1v, (size_t)p * DIM + c0 + 1) + u.y + fmaxf(bp4.y + accs[a][1], 0.0f);
            o.z = ldf(feats, f1v, (size_t)p * DIM + c0 + 2) + u.z + fmaxf(bp4.z + accs[a][2], 0.0f);
            o.w = ldf(feats, f1v, (size_t)p * DIM + c0 + 3) + u.w + fmaxf(bp4.w + accs[a][3], 0.0f);
            *(float4*)&out[(size_t)p * DIM + c0] = o;
        }
    }
}

extern "C" void kernel_launch(void* const* d_in, const int* in_sizes, int n_in,
                              void* d_out, int out_size, void* d_ws, size_t ws_size,
                              hipStream_t stream) {
    int N = in_sizes[0] / 3;
    int M = in_sizes[17];

    Ptrs P;
    for (int j = 0; j < 18; ++j) { P.p[j] = d_in[j]; P.sz[j] = in_sizes[j]; }

    size_t off = 0;
    auto alloc = [&](size_t bytes) -> void* {
        off = (off + 255) & ~(size_t)255;
        void* p = (void*)((char*)d_ws + off);
        off += bytes;
        return p;
    };
    int*    fl    = (int*)alloc(32 * 4);
    float*  Wf    = (float*)alloc((size_t)WTOT * 4);          // 858 KB
    float4* pnt4  = (float4*)alloc((size_t)N * 16);           // 800 KB
    float4* cent4 = (float4*)alloc((size_t)M * 16);           //  40 KB
    float*  cfbuf = (float*)alloc((size_t)M * DIM * 4);       // 1.28 MB
    int*    nbr   = (int*)alloc((size_t)M * KMAX * 4);        // 320 KB (total ~3.3 MB)

    probe_dtypes<<<1, 32, 0, stream>>>(P, fl);
    conv_params<<<(WTOT + 255) / 256, 256, 0, stream>>>(P, fl, Wf);
    prep_pts<<<(N + 255) / 256, 256, 0, stream>>>(d_in[0], fl, pnt4, N);
    prep_ctrs<<<(M + 255) / 256, 256, 0, stream>>>(d_in[17], fl, pnt4, cent4, M, N);
    ball_scan<<<M, 256, 0, stream>>>(pnt4, cent4, N, nbr);
    attn_ffn<<<M, 256, 0, stream>>>(nbr, d_in[1], d_in[17], fl, Wf, cfbuf, N);
    knn_select<<<(N + 3) / 4, 256, 0, stream>>>(pnt4, cent4, cfbuf, (float*)d_out, N, M);
    wp_out<<<(N + PB - 1) / PB, 256, 0, stream>>>(Wf, d_in[1], fl, (float*)d_out, N);
}

// Round 4
// 563.793 us; speedup vs baseline: 1.1400x; 1.0316x over previous
//
#include <hip/hip_runtime.h>
#include <hip/hip_bf16.h>
#include <stdint.h>

#define DIM    128
#define KMAX   32
#define LN_EPS 1e-5f
#define ATT_SCALE 0.17677669529663687f   // 32^-0.5
#define CAND   2048
#define WTOT   214400                    // 212992 weight f32 + 1408 param f32
#define PB     32                        // points per block in wp_out
#define NSTR   36                        // nft row stride (16B-aligned quads)
#define KSTR   132                       // s_kv row stride (16B-aligned quads)

typedef unsigned long long u64;
static __device__ __forceinline__ float bf2f(__hip_bfloat16 x) { return __bfloat162float(x); }

// ---- bit-exact replica of the np-fp32 distance pipeline (DO NOT TOUCH: passing) ----
static __device__ __forceinline__ float norm32(float x, float y, float z) {
    return __fadd_rn(__fadd_rn(__fmul_rn(x, x), __fmul_rn(y, y)), __fmul_rn(z, z));
}
static __device__ __forceinline__ float d2_32(float cx, float cy, float cz, float cw,
                                              float px, float py, float pz, float pw) {
    float dot = __fmaf_rn(cz, pz, __fmaf_rn(cy, py, __fmul_rn(cx, px)));
    return __fsub_rn(__fadd_rn(cw, pw), __fmul_rn(2.0f, dot));
}
static __device__ __forceinline__ float d2_to_dist(float d2) {
    d2 = fmaxf(d2, 0.0f);
    return (d2 > 0.0f) ? __fsqrt_rn(d2) : 0.0f;
}
static __device__ __forceinline__ float dist32(float cx, float cy, float cz, float cw,
                                               float px, float py, float pz, float pw) {
    return d2_to_dist(d2_32(cx, cy, cz, cw, px, py, pz, pw));
}

static __device__ __forceinline__ float ldf(const void* p, int f32, size_t i) {
    return f32 ? ((const float*)p)[i] : bf2f(((const __hip_bfloat16*)p)[i]);
}
static __device__ __forceinline__ int ldidx(const void* p, int i64, int m) {
    return i64 ? ((const int*)p)[2 * m] : ((const int*)p)[m];
}

struct Ptrs { const void* p[18]; int sz[18]; };

// ---------- probe: classify each input's dtype on-device (unchanged, passing) ----------
__global__ void probe_dtypes(Ptrs P, int* __restrict__ fl) {
    int j = threadIdx.x;
    if (j >= 18) return;
    const void* x = P.p[j];
    int sz = P.sz[j];
    int flag = 0;
    if (j == 17) {
        const int* ip = (const int*)x;
        int odd_zero = 1, even_nz = 0;
        for (int k = 0; k < 8 && 2 * k + 1 < sz * 2; ++k) {
            if (ip[2 * k + 1] != 0) odd_zero = 0;
            if (ip[2 * k] != 0) even_nz = 1;
        }
        flag = (odd_zero && even_nz) ? 1 : 0;
    } else {
        const __hip_bfloat16* hp = (const __hip_bfloat16*)x;
        int n = sz < 256 ? sz : 256;
        for (int i = 0; i < n; ++i) {
            float w = bf2f(hp[i]);
            if (w != w || fabsf(w) > 1000.0f) { flag = 1; break; }
        }
        if ((j == 7 || j == 9) && bf2f(hp[0]) == 0.0f) flag = 1;
    }
    fl[j] = flag;
}

// ---------- convert weights+params -> canonical fp32 (unchanged) ----------
__global__ __launch_bounds__(256) void conv_params(Ptrs P, const int* __restrict__ fl,
                                                   float* __restrict__ Wf) {
    int i = blockIdx.x * 256 + threadIdx.x;
    if (i >= WTOT) return;
    int j, off;
    if      (i < 16384)  { j = 2;  off = i; }
    else if (i < 32768)  { j = 3;  off = i - 16384; }
    else if (i < 49152)  { j = 4;  off = i - 32768; }
    else if (i < 65536)  { j = 5;  off = i - 49152; }
    else if (i < 131072) { j = 11; off = i - 65536; }
    else if (i < 196608) { j = 13; off = i - 131072; }
    else if (i < 212992) { j = 15; off = i - 196608; }
    else if (i < 213120) { j = 6;  off = i - 212992; }
    else if (i < 213248) { j = 7;  off = i - 213120; }
    else if (i < 213376) { j = 8;  off = i - 213248; }
    else if (i < 213504) { j = 9;  off = i - 213376; }
    else if (i < 213632) { j = 10; off = i - 213504; }
    else if (i < 214144) { j = 12; off = i - 213632; }
    else if (i < 214272) { j = 14; off = i - 214144; }
    else                 { j = 16; off = i - 214272; }
    Wf[i] = ldf(P.p[j], fl[j], off);
}

__global__ void prep_pts(const void* __restrict__ xyz, const int* __restrict__ fl,
                         float4* __restrict__ pnt4, int N) {
    int i = blockIdx.x * 256 + threadIdx.x;
    if (i < N) {
        int f = fl[0];
        float x = ldf(xyz, f, 3 * i + 0), y = ldf(xyz, f, 3 * i + 1), z = ldf(xyz, f, 3 * i + 2);
        pnt4[i] = make_float4(x, y, z, norm32(x, y, z));
    }
}

__global__ void prep_ctrs(const void* __restrict__ idxc, const int* __restrict__ fl,
                          const float4* __restrict__ pnt4, float4* __restrict__ cent4,
                          int M, int N) {
    int m = blockIdx.x * 256 + threadIdx.x;
    if (m < M) {
        int c = ldidx(idxc, fl[17], m);
        c = (c >= 0 && c < N) ? c : 0;
        cent4[m] = pnt4[c];
    }
}

// =================== kernel: ball query scan + top-32 select -> nbr_g (unchanged) ===================
__global__ __launch_bounds__(256) void ball_scan(
    const float4* __restrict__ pnt4,
    const float4* __restrict__ cent4,
    int N, int* __restrict__ nbr_g) {

    __shared__ u64 key[CAND];        // 16 KB
    __shared__ int s_cnt, s_ni[KMAX];

    int m = blockIdx.x, tid = threadIdx.x;
    float4 cc4 = cent4[m];

    if (tid == 0) s_cnt = 0;
    if (tid < KMAX) s_ni[tid] = -1;
    __syncthreads();

    for (int i = tid; i < N; i += 256) {
        float4 p = pnt4[i];
        float d2 = d2_32(cc4.x, cc4.y, cc4.z, cc4.w, p.x, p.y, p.z, p.w);
        if (d2 < 0.0901f) {
            float dist = d2_to_dist(d2);
            if (dist < 0.3f) {
                int pos = atomicAdd(&s_cnt, 1);
                if (pos < CAND)
                    key[pos] = ((u64)__float_as_uint(dist) << 32) | (unsigned)i;
            }
        }
    }
    __syncthreads();
    int cnt = min(s_cnt, CAND);

    for (int i = tid; i < cnt; i += 256) {
        u64 ki = key[i];
        int r = 0;
        for (int j = 0; j < cnt; ++j) r += (key[j] < ki) ? 1 : 0;
        if (r < KMAX) s_ni[r] = (int)(unsigned)(ki & 0xFFFFFFFFULL);
    }
    __syncthreads();
    if (tid < KMAX) nbr_g[m * KMAX + tid] = s_ni[tid];
}

// =================== kernel: attention + FFN -> cf (unchanged from v3, passing) ===================
#define NFT(cc, kk) R[(cc) * NSTR + (kk)]
#define SKV(kk, col) R[(kk) * KSTR + (col)]

__global__ __launch_bounds__(256) void attn_ffn(
    const int* __restrict__ nbr_g,
    const void* __restrict__ feats,
    const void* __restrict__ idxc,
    const int* __restrict__ fl,
    const float* __restrict__ Wf,
    float* __restrict__ cf_out, int N) {

    const float* Wqf = Wf;
    const float* Wkf = Wf + 16384;
    const float* Wvf = Wf + 32768;
    const float* Wof = Wf + 49152;
    const float* W1f = Wf + 65536;
    const float* W2f = Wf + 131072;
    const float* Pf  = Wf + 212992;

    __shared__ __align__(16) float R[128 * NSTR];   // 18.4KB: nft[128][36] | s_kv[32][132] | s_h+s_part
    __shared__ int   s_ni[KMAX];
    __shared__ __align__(16) float s_cf[DIM], s_q[DIM], s_attn[DIM], s_ao[DIM], s_x[DIM];
    __shared__ float s_red[4];

    int m = blockIdx.x, tid = threadIdx.x;
    int lane = tid & 63, wv = tid >> 6;
    int f1 = fl[1];
    int c = ldidx(idxc, fl[17], m);
    c = (c >= 0 && c < N) ? c : 0;

    if (tid < KMAX) s_ni[tid] = nbr_g[m * KMAX + tid];
    if (tid < 128) s_cf[tid] = ldf(feats, f1, (size_t)c * DIM + tid);
    __syncthreads();                                             // B1
    for (int t = tid; t < KMAX * DIM; t += 256) {
        int kk = t >> 7, cc = t & 127;
        int idx = s_ni[kk];
        float v = (idx >= 0 && idx < N) ? ldf(feats, f1, (size_t)idx * DIM + cc) : 0.0f;
        NFT(cc, kk) = v;
    }
    __syncthreads();                                             // B2

    if (tid < 128) {
        float acc = 0.0f;
#pragma unroll 4
        for (int i = 0; i < DIM; i += 4) {
            float4 a = *(const float4*)&s_cf[i];
            acc = fmaf(a.x, Wqf[(i + 0) * DIM + tid], acc);
            acc = fmaf(a.y, Wqf[(i + 1) * DIM + tid], acc);
            acc = fmaf(a.z, Wqf[(i + 2) * DIM + tid], acc);
            acc = fmaf(a.w, Wqf[(i + 3) * DIM + tid], acc);
        }
        s_q[tid] = acc;
    }

    // ---- K/V GEMM: register outer-product, thread = 4 k-rows x 4 cols, both mats ----
    int kq = tid >> 5, cq = tid & 31;
    int k0 = kq * 4, c0 = cq * 4;
    float ka[4][4], va[4][4];
#pragma unroll
    for (int j = 0; j < 4; ++j)
#pragma unroll
        for (int cc2 = 0; cc2 < 4; ++cc2) { ka[j][cc2] = 0.0f; va[j][cc2] = 0.0f; }

#pragma unroll 2
    for (int i = 0; i < DIM; ++i) {
        float4 n  = *(const float4*)&NFT(i, k0);
        float4 wk = *(const float4*)&Wkf[i * DIM + c0];
        float4 wv4 = *(const float4*)&Wvf[i * DIM + c0];
#pragma unroll
        for (int j = 0; j < 4; ++j) {
            float nj = (&n.x)[j];
            ka[j][0] = fmaf(nj, wk.x, ka[j][0]);
            ka[j][1] = fmaf(nj, wk.y, ka[j][1]);
            ka[j][2] = fmaf(nj, wk.z, ka[j][2]);
            ka[j][3] = fmaf(nj, wk.w, ka[j][3]);
            va[j][0] = fmaf(nj, wv4.x, va[j][0]);
            va[j][1] = fmaf(nj, wv4.y, va[j][1]);
            va[j][2] = fmaf(nj, wv4.z, va[j][2]);
            va[j][3] = fmaf(nj, wv4.w, va[j][3]);
        }
    }
    __syncthreads();                                             // B3: nft reads done, R reusable
#pragma unroll
    for (int j = 0; j < 4; ++j)
        *(float4*)&SKV(k0 + j, c0) = make_float4(ka[j][0], ka[j][1], ka[j][2], ka[j][3]);
    __syncthreads();                                             // B4

    if (tid < 128) {
        int h = tid >> 5, kk = tid & 31;
        float s = 0.0f;
#pragma unroll
        for (int d = 0; d < 32; ++d)
            s = fmaf(s_q[h * 32 + d], SKV(kk, h * 32 + d), s);
        s *= ATT_SCALE;
        if (s_ni[kk] < 0) s = -1e9f;
        // per-head softmax via 32-lane shuffle reduce (head = 32 contiguous lanes)
        float mx = s;
        for (int off = 16; off; off >>= 1) mx = fmaxf(mx, __shfl_xor(mx, off, 32));
        float e = expf(s - mx);
        float sm = e;
        for (int off = 16; off; off >>= 1) sm += __shfl_xor(sm, off, 32);
        sm = (sm > 0.0f) ? sm : 1.0f;
        s_attn[tid] = e / sm;
    }
    __syncthreads();                                             // B5: attn ready, K reads done
#pragma unroll
    for (int j = 0; j < 4; ++j)
        *(float4*)&SKV(k0 + j, c0) = make_float4(va[j][0], va[j][1], va[j][2], va[j][3]);
    __syncthreads();                                             // B6

    if (tid < 128) {
        int h = tid >> 5, d = tid & 31;
        float o = 0.0f;
#pragma unroll
        for (int kk = 0; kk < KMAX; ++kk)
            o = fmaf(s_attn[h * 32 + kk], SKV(kk, h * 32 + d), o);
        s_ao[d * 4 + h] = o;
    }
    __syncthreads();                                             // B7

    float upd = 0.0f;
    if (tid < 128) {
        upd = Pf[0 + tid];  // bo
#pragma unroll 4
        for (int i = 0; i < DIM; i += 4) {
            float4 a = *(const float4*)&s_ao[i];
            upd = fmaf(a.x, Wof[(i + 0) * DIM + tid], upd);
            upd = fmaf(a.y, Wof[(i + 1) * DIM + tid], upd);
            upd = fmaf(a.z, Wof[(i + 2) * DIM + tid], upd);
            upd = fmaf(a.w, Wof[(i + 3) * DIM + tid], upd);
        }
        float sum = upd;
        for (int off = 32; off; off >>= 1) sum += __shfl_xor(sum, off, 64);
        if (lane == 0) s_red[wv] = sum;
    }
    __syncthreads();                                             // B8
    float mu = (s_red[0] + s_red[1]) * (1.0f / 128.0f);
    float xc = upd - mu;
    if (tid < 128) {
        float q2 = xc * xc;
        for (int off = 32; off; off >>= 1) q2 += __shfl_xor(q2, off, 64);
        if (lane == 0) s_red[2 + wv] = q2;
    }
    __syncthreads();                                             // B9
    float var = (s_red[2] + s_red[3]) * (1.0f / 128.0f);
    float cf1 = 0.0f;
    if (tid < 128) {
        float rs = 1.0f / sqrtf(var + LN_EPS);
        float ln1 = fmaf(xc * rs, Pf[128 + tid], Pf[256 + tid]);  // n1w, n1b
        cf1 = s_cf[tid] + ln1;
        s_x[tid] = cf1;
    }
    __syncthreads();                                             // B10

    float* s_h = R;              // R[0..512): FFN hidden
    float* s_part = R + 512;     // R[512..768): W2 partials
#pragma unroll
    for (int jj = 0; jj < 2; ++jj) {
        int j = jj * 256 + tid;
        float a = Pf[640 + j];  // b1
#pragma unroll 4
        for (int i = 0; i < DIM; i += 4) {
            float4 v = *(const float4*)&s_x[i];
            a = fmaf(v.x, W1f[(i + 0) * 512 + j], a);
            a = fmaf(v.y, W1f[(i + 1) * 512 + j], a);
            a = fmaf(v.z, W1f[(i + 2) * 512 + j], a);
            a = fmaf(v.w, W1f[(i + 3) * 512 + j], a);
        }
        s_h[j] = fmaxf(a, 0.0f);
    }
    __syncthreads();                                             // B11

    int col = tid & 127;
    int half = tid >> 7;
    float f2 = (half == 0) ? Pf[1152 + col] : 0.0f;  // b2
    {
        int i0 = half * 256;
#pragma unroll 4
        for (int i = i0; i < i0 + 256; i += 4) {
            float4 v = *(const float4*)&s_h[i];
            f2 = fmaf(v.x, W2f[(i + 0) * DIM + col], f2);
            f2 = fmaf(v.y, W2f[(i + 1) * DIM + col], f2);
            f2 = fmaf(v.z, W2f[(i + 2) * DIM + col], f2);
            f2 = fmaf(v.w, W2f[(i + 3) * DIM + col], f2);
        }
    }
    float* s_part2 = s_part;
    s_part2[tid] = f2;
    __syncthreads();                                             // B12
    float ffn = 0.0f;
    if (tid < 128) {
        ffn = s_part2[tid] + s_part2[tid + 128];
        float sum = ffn;
        for (int off = 32; off; off >>= 1) sum += __shfl_xor(sum, off, 64);
        if (lane == 0) s_red[wv] = sum;
    }
    __syncthreads();                                             // B13
    mu = (s_red[0] + s_red[1]) * (1.0f / 128.0f);
    xc = ffn - mu;
    if (tid < 128) {
        float q2 = xc * xc;
        for (int off = 32; off; off >>= 1) q2 += __shfl_xor(q2, off, 64);
        if (lane == 0) s_red[2 + wv] = q2;
    }
    __syncthreads();                                             // B14
    var = (s_red[2] + s_red[3]) * (1.0f / 128.0f);
    if (tid < 128) {
        float rs2 = 1.0f / sqrtf(var + LN_EPS);
        float ln2 = fmaf(xc * rs2, Pf[384 + tid], Pf[512 + tid]);  // n2w, n2b
        cf_out[(size_t)m * DIM + tid] = cf1 + ln2;
    }
}

// =================== kernel: wave-per-point KNN select + upsample -> up (stored in d_out) ===================
// v4: threshold-pruned exact scan. Pass 1: per-lane min of raw d2 (1 vmin/candidate, no
// branches, no sqrt). T = 8th extracted butterfly-min of the 64 lane minima: the 8 removed
// lane minima are >=8 distinct elements <= T, so T >= true 8th-smallest d2 (dup removal only
// loosens the bound). Inflate by (1+2^-19) (clamp at 0) so rounded-dist ties at the 8th
// boundary are also captured (sqrt maps ~2ulp d2 -> 1ulp dist; 4x margin). Pass 2: only
// d2 <= Tuse candidates (~10-20 of 2500) get the sqrt + exact (dist,idx) u64 key, pushed
// to a per-wave LDS buffer. Pass 3: exact rank-select (keys unique -> total order), then
// walk sorted[0..7] ascending -> identical (d,w,wsum) sequence bitwise to the old merge.
// Buffer overflow (cnt>64) -> wave-uniform fallback to the proven full 8-deep scan+merge.
#define CSWAP(a, b) { if ((b) < (a)) { u64 t_ = (a); (a) = (b); (b) = t_; } }

__global__ __launch_bounds__(256) void knn_select(
    const float4* __restrict__ pnt4,
    const float4* __restrict__ cent4,
    const float* __restrict__ cf,
    float* __restrict__ upg,          // = d_out, N x 128 f32
    int N, int M) {

    __shared__ u64 s_buf[4][64];
    __shared__ u64 s_srt[4][8];
    __shared__ int s_cnt[4];

    int lane = threadIdx.x & 63;
    int wv   = threadIdx.x >> 6;
    int p = blockIdx.x * 4 + wv;
    bool own = (p < N);

    float4 pp = make_float4(0.f, 0.f, 0.f, 0.f);
    if (own) pp = pnt4[p];          // own is wave-uniform

    if (lane == 0) s_cnt[wv] = 0;
    __syncthreads();

    // ---- pass 1: per-lane min of raw d2 (cheap, unconditional) ----
    float vmn = 3.4e38f;
    for (int j = lane; j < M; j += 64) {
        float4 cc = cent4[j];
        float d2 = d2_32(cc.x, cc.y, cc.z, cc.w, pp.x, pp.y, pp.z, pp.w);
        vmn = fminf(vmn, d2);
    }
    // ---- T = 8th extracted wave-min of lane minima (guaranteed >= true 8th d2) ----
    float vv = vmn, T = 0.0f;
#pragma unroll
    for (int e = 0; e < 8; ++e) {
        float mv = vv;
        for (int off = 32; off; off >>= 1) mv = fminf(mv, __shfl_xor(mv, off, 64));
        T = mv;
        if (vv == mv) vv = 3.4e38f;
    }
    float Tuse = fmaxf(T, 0.0f) * 1.0000019073486328f;   // 1+2^-19 tie-capture margin

    // ---- pass 2: buffer exact keys for candidates with d2 <= Tuse ----
    for (int j = lane; j < M; j += 64) {
        float4 cc = cent4[j];
        float d2 = d2_32(cc.x, cc.y, cc.z, cc.w, pp.x, pp.y, pp.z, pp.w);
        if (d2 <= Tuse) {
            float dist = d2_to_dist(d2);
            u64 key = ((u64)__float_as_uint(dist) << 32) | (unsigned)j;
            int pos = atomicAdd(&s_cnt[wv], 1);
            if (pos < 64) s_buf[wv][pos] = key;
        }
    }
    __syncthreads();
    int cnt = s_cnt[wv];            // wave-uniform

    int   ki[8];
    float w8[8];
    float wsum = 0.0f;

    if (cnt <= 64 && M >= 8) {
        // ---- pass 3: exact rank-8 select over the buffer ----
        u64 myk = (lane < cnt) ? s_buf[wv][lane] : ~0ULL;
        int r = 0;
        for (int i = 0; i < cnt; ++i) {
            u64 o = s_buf[wv][i];
            r += (o < myk) ? 1 : 0;
        }
        if (lane < cnt && r < 8) s_srt[wv][r] = myk;
        // wave-internal LDS dep; ds ops complete in order per wave (lgkmcnt)
#pragma unroll
        for (int e = 0; e < 8; ++e) {
            u64 gm = s_srt[wv][e];
            float d = __uint_as_float((unsigned)(gm >> 32));
            int ci = (int)(unsigned)(gm & 0xFFFFFFFFULL);
            ci = (ci >= 0 && ci < M) ? ci : 0;
            float t = __fadd_rn(d, 1e-6f);
            float w = 1.0f / __fmul_rn(t, t);
            wsum += w;                               // ascending order (bit-exact)
            ki[e] = ci;
            w8[e] = w;
        }
    } else {
        // ---- fallback: proven full 8-deep scan + merge (R16 code) ----
        u64 f0 = ~0ULL, f1_ = ~0ULL, f2_ = ~0ULL, f3 = ~0ULL,
            f4 = ~0ULL, f5 = ~0ULL, f6 = ~0ULL, f7 = ~0ULL;
        for (int j = lane; j < M; j += 64) {
            float4 cc = cent4[j];
            float dist = dist32(cc.x, cc.y, cc.z, cc.w, pp.x, pp.y, pp.z, pp.w);
            u64 key = ((u64)__float_as_uint(dist) << 32) | (unsigned)j;
            if (key < f7) {
                f7 = key;
                CSWAP(f6, f7); CSWAP(f5, f6); CSWAP(f4, f5); CSWAP(f3, f4);
                CSWAP(f2_, f3); CSWAP(f1_, f2_); CSWAP(f0, f1_);
            }
        }
        int ptr2 = 0;
        u64 cur2 = f0;
        wsum = 0.0f;
#pragma unroll
        for (int e = 0; e < 8; ++e) {
            u64 v = cur2;
            for (int off = 32; off; off >>= 1) {
                u64 o = __shfl_down(v, off, 64);
                v = (o < v) ? o : v;
            }
            u64 gm = __shfl(v, 0, 64);
            float d = __uint_as_float((unsigned)(gm >> 32));
            int ci = (int)(unsigned)(gm & 0xFFFFFFFFULL);
            ci = (ci >= 0 && ci < M) ? ci : 0;
            float t = __fadd_rn(d, 1e-6f);
            float w = 1.0f / __fmul_rn(t, t);
            wsum += w;
            ki[e] = ci;
            w8[e] = w;
            if (cur2 == gm) {
                ptr2++;
                cur2 = (ptr2 == 1) ? f1_ : (ptr2 == 2) ? f2_ : (ptr2 == 3) ? f3 :
                       (ptr2 == 4) ? f4 : (ptr2 == 5) ? f5 : (ptr2 == 6) ? f6 :
                       (ptr2 == 7) ? f7 : ~0ULL;
            }
        }
    }

    float inv = 1.0f / wsum;
#pragma unroll
    for (int e = 0; e < 8; ++e) w8[e] *= inv;

    // ---- upsample: lane owns cols lane and lane+64 (k ascending, bit-exact) ----
    int c0 = lane, c1 = lane + 64;
    float up0 = 0.0f, up1 = 0.0f;
#pragma unroll
    for (int k = 0; k < 8; ++k) {
        const float* row = cf + (size_t)ki[k] * DIM;
        up0 = fmaf(w8[k], row[c0], up0);
        up1 = fmaf(w8[k], row[c1], up1);
    }

    if (own) {
        upg[(size_t)p * DIM + c0] = up0;
        upg[(size_t)p * DIM + c1] = up1;
    }
}

// =================== kernel: tiled Wp GEMM + epilogue, in place over d_out ===================
__global__ __launch_bounds__(256) void wp_out(
    const float* __restrict__ Wf,
    const void* __restrict__ feats,
    const int* __restrict__ fl,
    float* __restrict__ out,          // holds up on entry, final output on exit
    int N) {

    const float* Wpf = Wf + 196608;
    const float* bpf = Wf + 212992 + 1280;

    __shared__ __align__(16) float s_up[PB][132];   // +4 pad: 16B-aligned rows, bank spread

    int tid = threadIdx.x;
    int p0 = blockIdx.x * PB;

    // stage up tile (32 pts x 128), zero-fill past N
    for (int f = tid; f < PB * 32; f += 256) {
        int p = f >> 5, i4 = (f & 31) << 2;
        float4 v = make_float4(0.f, 0.f, 0.f, 0.f);
        if (p0 + p < N) v = *(const float4*)&out[(size_t)(p0 + p) * DIM + i4];
        *(float4*)&s_up[p][i4] = v;
    }
    __syncthreads();

    // thread = 4 cols x 4 pts register tile
    int cq = tid & 31, pq = tid >> 5;
    int c0 = cq << 2;
    int pA = pq << 2;

    float a00 = 0.f, a01 = 0.f, a02 = 0.f, a03 = 0.f;
    float a10 = 0.f, a11 = 0.f, a12 = 0.f, a13 = 0.f;
    float a20 = 0.f, a21 = 0.f, a22 = 0.f, a23 = 0.f;
    float a30 = 0.f, a31 = 0.f, a32 = 0.f, a33 = 0.f;

#pragma unroll 4
    for (int i = 0; i < DIM; ++i) {
        float4 w = *(const float4*)&Wpf[(size_t)i * DIM + c0];
        float u0 = s_up[pA + 0][i];
        float u1 = s_up[pA + 1][i];
        float u2 = s_up[pA + 2][i];
        float u3 = s_up[pA + 3][i];
        a00 = fmaf(u0, w.x, a00); a01 = fmaf(u0, w.y, a01);
        a02 = fmaf(u0, w.z, a02); a03 = fmaf(u0, w.w, a03);
        a10 = fmaf(u1, w.x, a10); a11 = fmaf(u1, w.y, a11);
        a12 = fmaf(u1, w.z, a12); a13 = fmaf(u1, w.w, a13);
        a20 = fmaf(u2, w.x, a20); a21 = fmaf(u2, w.y, a21);
        a22 = fmaf(u2, w.z, a22); a23 = fmaf(u2, w.w, a23);
        a30 = fmaf(u3, w.x, a30); a31 = fmaf(u3, w.y, a31);
        a32 = fmaf(u3, w.z, a32); a33 = fmaf(u3, w.w, a33);
    }

    int f1v = fl[1];
    float4 bp4 = make_float4(bpf[c0 + 0], bpf[c0 + 1], bpf[c0 + 2], bpf[c0 + 3]);

    float accs[4][4] = {{a00, a01, a02, a03}, {a10, a11, a12, a13},
                        {a20, a21, a22, a23}, {a30, a31, a32, a33}};
#pragma unroll
    for (int a = 0; a < 4; ++a) {
        int p = p0 + pA + a;
        if (p < N) {
            float4 u = *(const float4*)&s_up[pA + a][c0];
            float4 o;
            o.x = ldf(feats, f1v, (size_t)p * DIM + c0 + 0) + u.x + fmaxf(bp4.x + accs[a][0], 0.0f);
            o.y = ldf(feats, f1v, (size_t)p * DIM + c0 + 1) + u.y + fmaxf(bp4.y + accs[a][1], 0.0f);
            o.z = ldf(feats, f1v, (size_t)p * DIM + c0 + 2) + u.z + fmaxf(bp4.z + accs[a][2], 0.0f);
            o.w = ldf(feats, f1v, (size_t)p * DIM + c0 + 3) + u.w + fmaxf(bp4.w + accs[a][3], 0.0f);
            *(float4*)&out[(size_t)p * DIM + c0] = o;
        }
    }
}

extern "C" void kernel_launch(void* const* d_in, const int* in_sizes, int n_in,
                              void* d_out, int out_size, void* d_ws, size_t ws_size,
                              hipStream_t stream) {
    int N = in_sizes[0] / 3;
    int M = in_sizes[17];

    Ptrs P;
    for (int j = 0; j < 18; ++j) { P.p[j] = d_in[j]; P.sz[j] = in_sizes[j]; }

    size_t off = 0;
    auto alloc = [&](size_t bytes) -> void* {
        off = (off + 255) & ~(size_t)255;
        void* p = (void*)((char*)d_ws + off);
        off += bytes;
        return p;
    };
    int*    fl    = (int*)alloc(32 * 4);
    float*  Wf    = (float*)alloc((size_t)WTOT * 4);          // 858 KB
    float4* pnt4  = (float4*)alloc((size_t)N * 16);           // 800 KB
    float4* cent4 = (float4*)alloc((size_t)M * 16);           //  40 KB
    float*  cfbuf = (float*)alloc((size_t)M * DIM * 4);       // 1.28 MB
    int*    nbr   = (int*)alloc((size_t)M * KMAX * 4);        // 320 KB (total ~3.3 MB)

    probe_dtypes<<<1, 32, 0, stream>>>(P, fl);
    conv_params<<<(WTOT + 255) / 256, 256, 0, stream>>>(P, fl, Wf);
    prep_pts<<<(N + 255) / 256, 256, 0, stream>>>(d_in[0], fl, pnt4, N);
    prep_ctrs<<<(M + 255) / 256, 256, 0, stream>>>(d_in[17], fl, pnt4, cent4, M, N);
    ball_scan<<<M, 256, 0, stream>>>(pnt4, cent4, N, nbr);
    attn_ffn<<<M, 256, 0, stream>>>(nbr, d_in[1], d_in[17], fl, Wf, cfbuf, N);
    knn_select<<<(N + 3) / 4, 256, 0, stream>>>(pnt4, cent4, cfbuf, (float*)d_out, N, M);
    wp_out<<<(N + PB - 1) / PB, 256, 0, stream>>>(Wf, d_in[1], fl, (float*)d_out, N);
}

// Round 5
// 553.796 us; speedup vs baseline: 1.1605x; 1.0181x over previous
//
#include <hip/hip_runtime.h>
#include <hip/hip_bf16.h>
#include <stdint.h>

#define DIM    128
#define KMAX   32
#define LN_EPS 1e-5f
#define ATT_SCALE 0.17677669529663687f   // 32^-0.5
#define CAND   2048
#define WTOT   214400                    // 212992 weight f32 + 1408 param f32
#define PB     32                        // points per block in wp_out
#define NSTR2  72                        // nft row stride, 2 centers (16B-aligned quads)
#define KSTR   132                       // s_kv row stride (16B-aligned quads)

typedef unsigned long long u64;
static __device__ __forceinline__ float bf2f(__hip_bfloat16 x) { return __bfloat162float(x); }

// ---- bit-exact replica of the np-fp32 distance pipeline (DO NOT TOUCH: passing) ----
static __device__ __forceinline__ float norm32(float x, float y, float z) {
    return __fadd_rn(__fadd_rn(__fmul_rn(x, x), __fmul_rn(y, y)), __fmul_rn(z, z));
}
static __device__ __forceinline__ float d2_32(float cx, float cy, float cz, float cw,
                                              float px, float py, float pz, float pw) {
    float dot = __fmaf_rn(cz, pz, __fmaf_rn(cy, py, __fmul_rn(cx, px)));
    return __fsub_rn(__fadd_rn(cw, pw), __fmul_rn(2.0f, dot));
}
static __device__ __forceinline__ float d2_to_dist(float d2) {
    d2 = fmaxf(d2, 0.0f);
    return (d2 > 0.0f) ? __fsqrt_rn(d2) : 0.0f;
}
static __device__ __forceinline__ float dist32(float cx, float cy, float cz, float cw,
                                               float px, float py, float pz, float pw) {
    return d2_to_dist(d2_32(cx, cy, cz, cw, px, py, pz, pw));
}

static __device__ __forceinline__ float ldf(const void* p, int f32, size_t i) {
    return f32 ? ((const float*)p)[i] : bf2f(((const __hip_bfloat16*)p)[i]);
}
static __device__ __forceinline__ int ldidx(const void* p, int i64, int m) {
    return i64 ? ((const int*)p)[2 * m] : ((const int*)p)[m];
}

struct Ptrs { const void* p[18]; int sz[18]; };

// ---------- probe: classify each input's dtype on-device (unchanged, passing) ----------
__global__ void probe_dtypes(Ptrs P, int* __restrict__ fl) {
    int j = threadIdx.x;
    if (j >= 18) return;
    const void* x = P.p[j];
    int sz = P.sz[j];
    int flag = 0;
    if (j == 17) {
        const int* ip = (const int*)x;
        int odd_zero = 1, even_nz = 0;
        for (int k = 0; k < 8 && 2 * k + 1 < sz * 2; ++k) {
            if (ip[2 * k + 1] != 0) odd_zero = 0;
            if (ip[2 * k] != 0) even_nz = 1;
        }
        flag = (odd_zero && even_nz) ? 1 : 0;
    } else {
        const __hip_bfloat16* hp = (const __hip_bfloat16*)x;
        int n = sz < 256 ? sz : 256;
        for (int i = 0; i < n; ++i) {
            float w = bf2f(hp[i]);
            if (w != w || fabsf(w) > 1000.0f) { flag = 1; break; }
        }
        if ((j == 7 || j == 9) && bf2f(hp[0]) == 0.0f) flag = 1;
    }
    fl[j] = flag;
}

// ---------- convert weights+params -> canonical fp32 (unchanged) ----------
__global__ __launch_bounds__(256) void conv_params(Ptrs P, const int* __restrict__ fl,
                                                   float* __restrict__ Wf) {
    int i = blockIdx.x * 256 + threadIdx.x;
    if (i >= WTOT) return;
    int j, off;
    if      (i < 16384)  { j = 2;  off = i; }
    else if (i < 32768)  { j = 3;  off = i - 16384; }
    else if (i < 49152)  { j = 4;  off = i - 32768; }
    else if (i < 65536)  { j = 5;  off = i - 49152; }
    else if (i < 131072) { j = 11; off = i - 65536; }
    else if (i < 196608) { j = 13; off = i - 131072; }
    else if (i < 212992) { j = 15; off = i - 196608; }
    else if (i < 213120) { j = 6;  off = i - 212992; }
    else if (i < 213248) { j = 7;  off = i - 213120; }
    else if (i < 213376) { j = 8;  off = i - 213248; }
    else if (i < 213504) { j = 9;  off = i - 213376; }
    else if (i < 213632) { j = 10; off = i - 213504; }
    else if (i < 214144) { j = 12; off = i - 213632; }
    else if (i < 214272) { j = 14; off = i - 214144; }
    else                 { j = 16; off = i - 214272; }
    Wf[i] = ldf(P.p[j], fl[j], off);
}

__global__ void prep_pts(const void* __restrict__ xyz, const int* __restrict__ fl,
                         float4* __restrict__ pnt4, int N) {
    int i = blockIdx.x * 256 + threadIdx.x;
    if (i < N) {
        int f = fl[0];
        float x = ldf(xyz, f, 3 * i + 0), y = ldf(xyz, f, 3 * i + 1), z = ldf(xyz, f, 3 * i + 2);
        pnt4[i] = make_float4(x, y, z, norm32(x, y, z));
    }
}

__global__ void prep_ctrs(const void* __restrict__ idxc, const int* __restrict__ fl,
                          const float4* __restrict__ pnt4, float4* __restrict__ cent4,
                          int M, int N) {
    int m = blockIdx.x * 256 + threadIdx.x;
    if (m < M) {
        int c = ldidx(idxc, fl[17], m);
        c = (c >= 0 && c < N) ? c : 0;
        cent4[m] = pnt4[c];
    }
}

// =================== kernel: ball query scan + top-32 select -> nbr_g (unchanged) ===================
__global__ __launch_bounds__(256) void ball_scan(
    const float4* __restrict__ pnt4,
    const float4* __restrict__ cent4,
    int N, int* __restrict__ nbr_g) {

    __shared__ u64 key[CAND];        // 16 KB
    __shared__ int s_cnt, s_ni[KMAX];

    int m = blockIdx.x, tid = threadIdx.x;
    float4 cc4 = cent4[m];

    if (tid == 0) s_cnt = 0;
    if (tid < KMAX) s_ni[tid] = -1;
    __syncthreads();

    for (int i = tid; i < N; i += 256) {
        float4 p = pnt4[i];
        float d2 = d2_32(cc4.x, cc4.y, cc4.z, cc4.w, p.x, p.y, p.z, p.w);
        if (d2 < 0.0901f) {
            float dist = d2_to_dist(d2);
            if (dist < 0.3f) {
                int pos = atomicAdd(&s_cnt, 1);
                if (pos < CAND)
                    key[pos] = ((u64)__float_as_uint(dist) << 32) | (unsigned)i;
            }
        }
    }
    __syncthreads();
    int cnt = min(s_cnt, CAND);

    for (int i = tid; i < cnt; i += 256) {
        u64 ki = key[i];
        int r = 0;
        for (int j = 0; j < cnt; ++j) r += (key[j] < ki) ? 1 : 0;
        if (r < KMAX) s_ni[r] = (int)(unsigned)(ki & 0xFFFFFFFFULL);
    }
    __syncthreads();
    if (tid < KMAX) nbr_g[m * KMAX + tid] = s_ni[tid];
}

// =================== kernel: attention + FFN -> cf ===================
// v5: TWO centers per block (1250 blocks). Doubles arithmetic intensity on the shared
// weight stream (per i-step: 2 LDS b128 + same 2 weight float4 loads + 64 fma vs 32),
// makes EVERY phase 256-thread (center = tid>>7; QK/PV/Wo/LN had 128 idle lanes in v4),
// and amortizes gather latency (32 outstanding loads/thread). LDS: nft[128][72] region R
// (36.9KB); after B3 it is re-used as s_kv[64][132] (33.8KB) + s_q/s_attn/s_ao in the
// 768-float tail. Per-output fma chains (i ascending, identical operands) and the FFN2
// split-K association (b2+sum0..255)+(sum256..511) are unchanged -> bit-exact vs v4.
#define NFT2(cc, kk) R[(cc) * NSTR2 + (kk)]
#define SKV2(kk, col) R[(kk) * KSTR + (col)]

__global__ __launch_bounds__(256, 4) void attn_ffn(
    const int* __restrict__ nbr_g,
    const void* __restrict__ feats,
    const void* __restrict__ idxc,
    const int* __restrict__ fl,
    const float* __restrict__ Wf,
    float* __restrict__ cf_out, int N, int M) {

    const float* Wqf = Wf;
    const float* Wkf = Wf + 16384;
    const float* Wvf = Wf + 32768;
    const float* Wof = Wf + 49152;
    const float* W1f = Wf + 65536;
    const float* W2f = Wf + 131072;
    const float* Pf  = Wf + 212992;

    __shared__ __align__(16) float R[128 * NSTR2];   // 36.9KB: nft[128][72] | s_kv[64][132]+tail
    __shared__ int   s_ni[2 * KMAX];
    __shared__ __align__(16) float s_cf[256], s_x[256];
    __shared__ float s_red[8];

    int tid = threadIdx.x;
    int lane = tid & 63, wv = tid >> 6;
    int center = tid >> 7, col = tid & 127;
    int m0 = blockIdx.x * 2;
    int f1 = fl[1], fi = fl[17];

    if (tid < 64) {
        int m2 = m0 + (tid >> 5);
        s_ni[tid] = (m2 < M) ? nbr_g[m2 * KMAX + (tid & 31)] : -1;
    }
    {
        int m2 = m0 + center; m2 = (m2 < M) ? m2 : (M - 1);
        int c = ldidx(idxc, fi, m2);
        c = (c >= 0 && c < N) ? c : 0;
        s_cf[tid] = ldf(feats, f1, (size_t)c * DIM + col);
    }
    __syncthreads();                                             // B1
    for (int t = tid; t < 64 * DIM; t += 256) {
        int kk2 = t >> 7, cc = t & 127;
        int idx = s_ni[kk2];
        float v = (idx >= 0 && idx < N) ? ldf(feats, f1, (size_t)idx * DIM + cc) : 0.0f;
        NFT2(cc, kk2) = v;
    }
    __syncthreads();                                             // B2

    // ---- K/V GEMM: thread = 8 k-rows (both centers' range) x 4 cols, both mats ----
    int kq = tid >> 5, cq = tid & 31;
    int k0 = kq * 8, c0 = cq * 4;
    float ka[8][4], va[8][4];
#pragma unroll
    for (int j = 0; j < 8; ++j)
#pragma unroll
        for (int cc2 = 0; cc2 < 4; ++cc2) { ka[j][cc2] = 0.0f; va[j][cc2] = 0.0f; }

#pragma unroll 2
    for (int i = 0; i < DIM; ++i) {
        float4 n0  = *(const float4*)&NFT2(i, k0);
        float4 n1  = *(const float4*)&NFT2(i, k0 + 4);
        float4 wk  = *(const float4*)&Wkf[i * DIM + c0];
        float4 wv4 = *(const float4*)&Wvf[i * DIM + c0];
        float nn[8] = {n0.x, n0.y, n0.z, n0.w, n1.x, n1.y, n1.z, n1.w};
#pragma unroll
        for (int j = 0; j < 8; ++j) {
            float nj = nn[j];
            ka[j][0] = fmaf(nj, wk.x, ka[j][0]);
            ka[j][1] = fmaf(nj, wk.y, ka[j][1]);
            ka[j][2] = fmaf(nj, wk.z, ka[j][2]);
            ka[j][3] = fmaf(nj, wk.w, ka[j][3]);
            va[j][0] = fmaf(nj, wv4.x, va[j][0]);
            va[j][1] = fmaf(nj, wv4.y, va[j][1]);
            va[j][2] = fmaf(nj, wv4.z, va[j][2]);
            va[j][3] = fmaf(nj, wv4.w, va[j][3]);
        }
    }
    __syncthreads();                                             // B3: nft dead, R reusable

    float* s_q    = R + 8448;    // tail of R: 64*132 = 8448
    float* s_attn = R + 8704;
    float* s_ao   = R + 8960;    // tail ends at 9216 = 128*72

#pragma unroll
    for (int j = 0; j < 8; ++j)
        *(float4*)&SKV2(k0 + j, c0) = make_float4(ka[j][0], ka[j][1], ka[j][2], ka[j][3]);
    // Q GEMM (all 256 threads: one output col per center)
    {
        float acc = 0.0f;
        const float* cfc = s_cf + center * 128;
#pragma unroll 4
        for (int i = 0; i < DIM; i += 4) {
            float4 a = *(const float4*)&cfc[i];
            acc = fmaf(a.x, Wqf[(i + 0) * DIM + col], acc);
            acc = fmaf(a.y, Wqf[(i + 1) * DIM + col], acc);
            acc = fmaf(a.z, Wqf[(i + 2) * DIM + col], acc);
            acc = fmaf(a.w, Wqf[(i + 3) * DIM + col], acc);
        }
        s_q[tid] = acc;
    }
    __syncthreads();                                             // B4

    // ---- QK + softmax: all 256 threads; head = 32 contiguous lanes ----
    {
        int h = (tid >> 5) & 3, kk = tid & 31;
        float s = 0.0f;
#pragma unroll
        for (int d = 0; d < 32; ++d)
            s = fmaf(s_q[center * 128 + h * 32 + d], SKV2(center * 32 + kk, h * 32 + d), s);
        s *= ATT_SCALE;
        if (s_ni[center * 32 + kk] < 0) s = -1e9f;
        float mx = s;
        for (int off = 16; off; off >>= 1) mx = fmaxf(mx, __shfl_xor(mx, off, 32));
        float e = expf(s - mx);
        float sm = e;
        for (int off = 16; off; off >>= 1) sm += __shfl_xor(sm, off, 32);
        sm = (sm > 0.0f) ? sm : 1.0f;
        s_attn[tid] = e / sm;
    }
    __syncthreads();                                             // B5: K reads done
#pragma unroll
    for (int j = 0; j < 8; ++j)
        *(float4*)&SKV2(k0 + j, c0) = make_float4(va[j][0], va[j][1], va[j][2], va[j][3]);
    __syncthreads();                                             // B6

    // ---- PV: all 256 threads ----
    {
        int h = (tid >> 5) & 3, d = tid & 31;
        float o = 0.0f;
#pragma unroll
        for (int kk = 0; kk < KMAX; ++kk)
            o = fmaf(s_attn[center * 128 + h * 32 + kk], SKV2(center * 32 + kk, h * 32 + d), o);
        s_ao[center * 128 + d * 4 + h] = o;
    }
    __syncthreads();                                             // B7

    // ---- Wo + LN1 (all 256 threads; per-center reduce over its 2 waves) ----
    float upd = Pf[0 + col];  // bo
    {
#pragma unroll 4
        for (int i = 0; i < DIM; i += 4) {
            float4 a = *(const float4*)&s_ao[center * 128 + i];
            upd = fmaf(a.x, Wof[(i + 0) * DIM + col], upd);
            upd = fmaf(a.y, Wof[(i + 1) * DIM + col], upd);
            upd = fmaf(a.z, Wof[(i + 2) * DIM + col], upd);
            upd = fmaf(a.w, Wof[(i + 3) * DIM + col], upd);
        }
        float sum = upd;
        for (int off = 32; off; off >>= 1) sum += __shfl_xor(sum, off, 64);
        if (lane == 0) s_red[wv] = sum;
    }
    __syncthreads();                                             // B8
    float mu = (s_red[center * 2] + s_red[center * 2 + 1]) * (1.0f / 128.0f);
    float xc = upd - mu;
    {
        float q2 = xc * xc;
        for (int off = 32; off; off >>= 1) q2 += __shfl_xor(q2, off, 64);
        if (lane == 0) s_red[4 + wv] = q2;
    }
    __syncthreads();                                             // B9
    float var = (s_red[4 + center * 2] + s_red[5 + center * 2]) * (1.0f / 128.0f);
    float cf1;
    {
        float rs = 1.0f / sqrtf(var + LN_EPS);
        float ln1 = fmaf(xc * rs, Pf[128 + col], Pf[256 + col]);  // n1w, n1b
        cf1 = s_cf[tid] + ln1;
        s_x[tid] = cf1;
    }
    __syncthreads();                                             // B10

    // ---- FFN1: 4 outputs/thread (s_h = R[0..1024), V dead) ----
    float* s_h = R;
#pragma unroll
    for (int jj = 0; jj < 4; ++jj) {
        int j = col + 128 * jj;
        float a = Pf[640 + j];  // b1
#pragma unroll 4
        for (int i = 0; i < DIM; i += 4) {
            float4 v = *(const float4*)&s_x[center * 128 + i];
            a = fmaf(v.x, W1f[(i + 0) * 512 + j], a);
            a = fmaf(v.y, W1f[(i + 1) * 512 + j], a);
            a = fmaf(v.z, W1f[(i + 2) * 512 + j], a);
            a = fmaf(v.w, W1f[(i + 3) * 512 + j], a);
        }
        s_h[center * 512 + j] = fmaxf(a, 0.0f);
    }
    __syncthreads();                                             // B11

    // ---- FFN2: one output/thread, split-K halves kept in v4's association ----
    float fa = Pf[1152 + col];  // b2
    {
        const float* hc = s_h + center * 512;
#pragma unroll 4
        for (int i = 0; i < 256; i += 4) {
            float4 v = *(const float4*)&hc[i];
            fa = fmaf(v.x, W2f[(i + 0) * DIM + col], fa);
            fa = fmaf(v.y, W2f[(i + 1) * DIM + col], fa);
            fa = fmaf(v.z, W2f[(i + 2) * DIM + col], fa);
            fa = fmaf(v.w, W2f[(i + 3) * DIM + col], fa);
        }
    }
    float fb = 0.0f;
    {
        const float* hc = s_h + center * 512;
#pragma unroll 4
        for (int i = 256; i < 512; i += 4) {
            float4 v = *(const float4*)&hc[i];
            fb = fmaf(v.x, W2f[(i + 0) * DIM + col], fb);
            fb = fmaf(v.y, W2f[(i + 1) * DIM + col], fb);
            fb = fmaf(v.z, W2f[(i + 2) * DIM + col], fb);
            fb = fmaf(v.w, W2f[(i + 3) * DIM + col], fb);
        }
    }
    float ffn = fa + fb;
    {
        float sum = ffn;
        for (int off = 32; off; off >>= 1) sum += __shfl_xor(sum, off, 64);
        if (lane == 0) s_red[wv] = sum;
    }
    __syncthreads();                                             // B12
    mu = (s_red[center * 2] + s_red[center * 2 + 1]) * (1.0f / 128.0f);
    xc = ffn - mu;
    {
        float q2 = xc * xc;
        for (int off = 32; off; off >>= 1) q2 += __shfl_xor(q2, off, 64);
        if (lane == 0) s_red[4 + wv] = q2;
    }
    __syncthreads();                                             // B13
    var = (s_red[4 + center * 2] + s_red[5 + center * 2]) * (1.0f / 128.0f);
    {
        float rs2 = 1.0f / sqrtf(var + LN_EPS);
        float ln2 = fmaf(xc * rs2, Pf[384 + col], Pf[512 + col]);  // n2w, n2b
        int m2 = m0 + center;
        if (m2 < M) cf_out[(size_t)m2 * DIM + col] = cf1 + ln2;
    }
}

// =================== kernel: wave-per-point KNN select + upsample -> up (stored in d_out) ===================
// v4: threshold-pruned exact scan (unchanged, passing).
#define CSWAP(a, b) { if ((b) < (a)) { u64 t_ = (a); (a) = (b); (b) = t_; } }

__global__ __launch_bounds__(256) void knn_select(
    const float4* __restrict__ pnt4,
    const float4* __restrict__ cent4,
    const float* __restrict__ cf,
    float* __restrict__ upg,          // = d_out, N x 128 f32
    int N, int M) {

    __shared__ u64 s_buf[4][64];
    __shared__ u64 s_srt[4][8];
    __shared__ int s_cnt[4];

    int lane = threadIdx.x & 63;
    int wv   = threadIdx.x >> 6;
    int p = blockIdx.x * 4 + wv;
    bool own = (p < N);

    float4 pp = make_float4(0.f, 0.f, 0.f, 0.f);
    if (own) pp = pnt4[p];          // own is wave-uniform

    if (lane == 0) s_cnt[wv] = 0;
    __syncthreads();

    // ---- pass 1: per-lane min of raw d2 (cheap, unconditional) ----
    float vmn = 3.4e38f;
    for (int j = lane; j < M; j += 64) {
        float4 cc = cent4[j];
        float d2 = d2_32(cc.x, cc.y, cc.z, cc.w, pp.x, pp.y, pp.z, pp.w);
        vmn = fminf(vmn, d2);
    }
    // ---- T = 8th extracted wave-min of lane minima (guaranteed >= true 8th d2) ----
    float vv = vmn, T = 0.0f;
#pragma unroll
    for (int e = 0; e < 8; ++e) {
        float mv = vv;
        for (int off = 32; off; off >>= 1) mv = fminf(mv, __shfl_xor(mv, off, 64));
        T = mv;
        if (vv == mv) vv = 3.4e38f;
    }
    float Tuse = fmaxf(T, 0.0f) * 1.0000019073486328f;   // 1+2^-19 tie-capture margin

    // ---- pass 2: buffer exact keys for candidates with d2 <= Tuse ----
    for (int j = lane; j < M; j += 64) {
        float4 cc = cent4[j];
        float d2 = d2_32(cc.x, cc.y, cc.z, cc.w, pp.x, pp.y, pp.z, pp.w);
        if (d2 <= Tuse) {
            float dist = d2_to_dist(d2);
            u64 key = ((u64)__float_as_uint(dist) << 32) | (unsigned)j;
            int pos = atomicAdd(&s_cnt[wv], 1);
            if (pos < 64) s_buf[wv][pos] = key;
        }
    }
    __syncthreads();
    int cnt = s_cnt[wv];            // wave-uniform

    int   ki[8];
    float w8[8];
    float wsum = 0.0f;

    if (cnt <= 64 && M >= 8) {
        // ---- pass 3: exact rank-8 select over the buffer ----
        u64 myk = (lane < cnt) ? s_buf[wv][lane] : ~0ULL;
        int r = 0;
        for (int i = 0; i < cnt; ++i) {
            u64 o = s_buf[wv][i];
            r += (o < myk) ? 1 : 0;
        }
        if (lane < cnt && r < 8) s_srt[wv][r] = myk;
        // wave-internal LDS dep; ds ops complete in order per wave (lgkmcnt)
#pragma unroll
        for (int e = 0; e < 8; ++e) {
            u64 gm = s_srt[wv][e];
            float d = __uint_as_float((unsigned)(gm >> 32));
            int ci = (int)(unsigned)(gm & 0xFFFFFFFFULL);
            ci = (ci >= 0 && ci < M) ? ci : 0;
            float t = __fadd_rn(d, 1e-6f);
            float w = 1.0f / __fmul_rn(t, t);
            wsum += w;                               // ascending order (bit-exact)
            ki[e] = ci;
            w8[e] = w;
        }
    } else {
        // ---- fallback: proven full 8-deep scan + merge (R16 code) ----
        u64 f0 = ~0ULL, f1_ = ~0ULL, f2_ = ~0ULL, f3 = ~0ULL,
            f4 = ~0ULL, f5 = ~0ULL, f6 = ~0ULL, f7 = ~0ULL;
        for (int j = lane; j < M; j += 64) {
            float4 cc = cent4[j];
            float dist = dist32(cc.x, cc.y, cc.z, cc.w, pp.x, pp.y, pp.z, pp.w);
            u64 key = ((u64)__float_as_uint(dist) << 32) | (unsigned)j;
            if (key < f7) {
                f7 = key;
                CSWAP(f6, f7); CSWAP(f5, f6); CSWAP(f4, f5); CSWAP(f3, f4);
                CSWAP(f2_, f3); CSWAP(f1_, f2_); CSWAP(f0, f1_);
            }
        }
        int ptr2 = 0;
        u64 cur2 = f0;
        wsum = 0.0f;
#pragma unroll
        for (int e = 0; e < 8; ++e) {
            u64 v = cur2;
            for (int off = 32; off; off >>= 1) {
                u64 o = __shfl_down(v, off, 64);
                v = (o < v) ? o : v;
            }
            u64 gm = __shfl(v, 0, 64);
            float d = __uint_as_float((unsigned)(gm >> 32));
            int ci = (int)(unsigned)(gm & 0xFFFFFFFFULL);
            ci = (ci >= 0 && ci < M) ? ci : 0;
            float t = __fadd_rn(d, 1e-6f);
            float w = 1.0f / __fmul_rn(t, t);
            wsum += w;
            ki[e] = ci;
            w8[e] = w;
            if (cur2 == gm) {
                ptr2++;
                cur2 = (ptr2 == 1) ? f1_ : (ptr2 == 2) ? f2_ : (ptr2 == 3) ? f3 :
                       (ptr2 == 4) ? f4 : (ptr2 == 5) ? f5 : (ptr2 == 6) ? f6 :
                       (ptr2 == 7) ? f7 : ~0ULL;
            }
        }
    }

    float inv = 1.0f / wsum;
#pragma unroll
    for (int e = 0; e < 8; ++e) w8[e] *= inv;

    // ---- upsample: lane owns cols lane and lane+64 (k ascending, bit-exact) ----
    int c0 = lane, c1 = lane + 64;
    float up0 = 0.0f, up1 = 0.0f;
#pragma unroll
    for (int k = 0; k < 8; ++k) {
        const float* row = cf + (size_t)ki[k] * DIM;
        up0 = fmaf(w8[k], row[c0], up0);
        up1 = fmaf(w8[k], row[c1], up1);
    }

    if (own) {
        upg[(size_t)p * DIM + c0] = up0;
        upg[(size_t)p * DIM + c1] = up1;
    }
}

// =================== kernel: tiled Wp GEMM + epilogue, in place over d_out ===================
__global__ __launch_bounds__(256) void wp_out(
    const float* __restrict__ Wf,
    const void* __restrict__ feats,
    const int* __restrict__ fl,
    float* __restrict__ out,          // holds up on entry, final output on exit
    int N) {

    const float* Wpf = Wf + 196608;
    const float* bpf = Wf + 212992 + 1280;

    __shared__ __align__(16) float s_up[PB][132];   // +4 pad: 16B-aligned rows, bank spread

    int tid = threadIdx.x;
    int p0 = blockIdx.x * PB;

    // stage up tile (32 pts x 128), zero-fill past N
    for (int f = tid; f < PB * 32; f += 256) {
        int p = f >> 5, i4 = (f & 31) << 2;
        float4 v = make_float4(0.f, 0.f, 0.f, 0.f);
        if (p0 + p < N) v = *(const float4*)&out[(size_t)(p0 + p) * DIM + i4];
        *(float4*)&s_up[p][i4] = v;
    }
    __syncthreads();

    // thread = 4 cols x 4 pts register tile
    int cq = tid & 31, pq = tid >> 5;
    int c0 = cq << 2;
    int pA = pq << 2;

    float a00 = 0.f, a01 = 0.f, a02 = 0.f, a03 = 0.f;
    float a10 = 0.f, a11 = 0.f, a12 = 0.f, a13 = 0.f;
    float a20 = 0.f, a21 = 0.f, a22 = 0.f, a23 = 0.f;
    float a30 = 0.f, a31 = 0.f, a32 = 0.f, a33 = 0.f;

#pragma unroll 4
    for (int i = 0; i < DIM; ++i) {
        float4 w = *(const float4*)&Wpf[(size_t)i * DIM + c0];
        float u0 = s_up[pA + 0][i];
        float u1 = s_up[pA + 1][i];
        float u2 = s_up[pA + 2][i];
        float u3 = s_up[pA + 3][i];
        a00 = fmaf(u0, w.x, a00); a01 = fmaf(u0, w.y, a01);
        a02 = fmaf(u0, w.z, a02); a03 = fmaf(u0, w.w, a03);
        a10 = fmaf(u1, w.x, a10); a11 = fmaf(u1, w.y, a11);
        a12 = fmaf(u1, w.z, a12); a13 = fmaf(u1, w.w, a13);
        a20 = fmaf(u2, w.x, a20); a21 = fmaf(u2, w.y, a21);
        a22 = fmaf(u2, w.z, a22); a23 = fmaf(u2, w.w, a23);
        a30 = fmaf(u3, w.x, a30); a31 = fmaf(u3, w.y, a31);
        a32 = fmaf(u3, w.z, a32); a33 = fmaf(u3, w.w, a33);
    }

    int f1v = fl[1];
    float4 bp4 = make_float4(bpf[c0 + 0], bpf[c0 + 1], bpf[c0 + 2], bpf[c0 + 3]);

    float accs[4][4] = {{a00, a01, a02, a03}, {a10, a11, a12, a13},
                        {a20, a21, a22, a23}, {a30, a31, a32, a33}};
#pragma unroll
    for (int a = 0; a < 4; ++a) {
        int p = p0 + pA + a;
        if (p < N) {
            float4 u = *(const float4*)&s_up[pA + a][c0];
            float4 o;
            o.x = ldf(feats, f1v, (size_t)p * DIM + c0 + 0) + u.x + fmaxf(bp4.x + accs[a][0], 0.0f);
            o.y = ldf(feats, f1v, (size_t)p * DIM + c0 + 1) + u.y + fmaxf(bp4.y + accs[a][1], 0.0f);
            o.z = ldf(feats, f1v, (size_t)p * DIM + c0 + 2) + u.z + fmaxf(bp4.z + accs[a][2], 0.0f);
            o.w = ldf(feats, f1v, (size_t)p * DIM + c0 + 3) + u.w + fmaxf(bp4.w + accs[a][3], 0.0f);
            *(float4*)&out[(size_t)p * DIM + c0] = o;
        }
    }
}

extern "C" void kernel_launch(void* const* d_in, const int* in_sizes, int n_in,
                              void* d_out, int out_size, void* d_ws, size_t ws_size,
                              hipStream_t stream) {
    int N = in_sizes[0] / 3;
    int M = in_sizes[17];

    Ptrs P;
    for (int j = 0; j < 18; ++j) { P.p[j] = d_in[j]; P.sz[j] = in_sizes[j]; }

    size_t off = 0;
    auto alloc = [&](size_t bytes) -> void* {
        off = (off + 255) & ~(size_t)255;
        void* p = (void*)((char*)d_ws + off);
        off += bytes;
        return p;
    };
    int*    fl    = (int*)alloc(32 * 4);
    float*  Wf    = (float*)alloc((size_t)WTOT * 4);          // 858 KB
    float4* pnt4  = (float4*)alloc((size_t)N * 16);           // 800 KB
    float4* cent4 = (float4*)alloc((size_t)M * 16);           //  40 KB
    float*  cfbuf = (float*)alloc((size_t)M * DIM * 4);       // 1.28 MB
    int*    nbr   = (int*)alloc((size_t)M * KMAX * 4);        // 320 KB (total ~3.3 MB)

    probe_dtypes<<<1, 32, 0, stream>>>(P, fl);
    conv_params<<<(WTOT + 255) / 256, 256, 0, stream>>>(P, fl, Wf);
    prep_pts<<<(N + 255) / 256, 256, 0, stream>>>(d_in[0], fl, pnt4, N);
    prep_ctrs<<<(M + 255) / 256, 256, 0, stream>>>(d_in[17], fl, pnt4, cent4, M, N);
    ball_scan<<<M, 256, 0, stream>>>(pnt4, cent4, N, nbr);
    attn_ffn<<<(M + 1) / 2, 256, 0, stream>>>(nbr, d_in[1], d_in[17], fl, Wf, cfbuf, N, M);
    knn_select<<<(N + 3) / 4, 256, 0, stream>>>(pnt4, cent4, cfbuf, (float*)d_out, N, M);
    wp_out<<<(N + PB - 1) / PB, 256, 0, stream>>>(Wf, d_in[1], fl, (float*)d_out, N);
}

// Round 6
// 511.710 us; speedup vs baseline: 1.2560x; 1.0822x over previous
//
#include <hip/hip_runtime.h>
#include <hip/hip_bf16.h>
#include <stdint.h>

#define DIM    128
#define KMAX   32
#define LN_EPS 1e-5f
#define ATT_SCALE 0.17677669529663687f   // 32^-0.5
#define CAND   2048
#define WTOT   214400                    // 212992 weight f32 + 1408 param f32
#define PB     32                        // points per block in wp_out
#define NSTR2  72                        // nft row stride, 2 centers (16B-aligned quads)
#define KSTR   132                       // s_kv row stride (16B-aligned quads)

typedef unsigned long long u64;
static __device__ __forceinline__ float bf2f(__hip_bfloat16 x) { return __bfloat162float(x); }

// ---- bit-exact replica of the np-fp32 distance pipeline (DO NOT TOUCH: passing) ----
static __device__ __forceinline__ float norm32(float x, float y, float z) {
    return __fadd_rn(__fadd_rn(__fmul_rn(x, x), __fmul_rn(y, y)), __fmul_rn(z, z));
}
static __device__ __forceinline__ float d2_32(float cx, float cy, float cz, float cw,
                                              float px, float py, float pz, float pw) {
    float dot = __fmaf_rn(cz, pz, __fmaf_rn(cy, py, __fmul_rn(cx, px)));
    return __fsub_rn(__fadd_rn(cw, pw), __fmul_rn(2.0f, dot));
}
static __device__ __forceinline__ float d2_to_dist(float d2) {
    d2 = fmaxf(d2, 0.0f);
    return (d2 > 0.0f) ? __fsqrt_rn(d2) : 0.0f;
}
static __device__ __forceinline__ float dist32(float cx, float cy, float cz, float cw,
                                               float px, float py, float pz, float pw) {
    return d2_to_dist(d2_32(cx, cy, cz, cw, px, py, pz, pw));
}

static __device__ __forceinline__ float ldf(const void* p, int f32, size_t i) {
    return f32 ? ((const float*)p)[i] : bf2f(((const __hip_bfloat16*)p)[i]);
}
static __device__ __forceinline__ int ldidx(const void* p, int i64, int m) {
    return i64 ? ((const int*)p)[2 * m] : ((const int*)p)[m];
}

struct Ptrs { const void* p[18]; int sz[18]; };

// ---------- probe: classify each input's dtype on-device (unchanged, passing) ----------
__global__ void probe_dtypes(Ptrs P, int* __restrict__ fl) {
    int j = threadIdx.x;
    if (j >= 18) return;
    const void* x = P.p[j];
    int sz = P.sz[j];
    int flag = 0;
    if (j == 17) {
        const int* ip = (const int*)x;
        int odd_zero = 1, even_nz = 0;
        for (int k = 0; k < 8 && 2 * k + 1 < sz * 2; ++k) {
            if (ip[2 * k + 1] != 0) odd_zero = 0;
            if (ip[2 * k] != 0) even_nz = 1;
        }
        flag = (odd_zero && even_nz) ? 1 : 0;
    } else {
        const __hip_bfloat16* hp = (const __hip_bfloat16*)x;
        int n = sz < 256 ? sz : 256;
        for (int i = 0; i < n; ++i) {
            float w = bf2f(hp[i]);
            if (w != w || fabsf(w) > 1000.0f) { flag = 1; break; }
        }
        if ((j == 7 || j == 9) && bf2f(hp[0]) == 0.0f) flag = 1;
    }
    fl[j] = flag;
}

// ---------- fused: convert weights+params AND build pnt4/cent4 (saves 2 launches) ----------
// cent4 computed directly from xyz with the same norm32 ops -> bit-identical to the old
// prep_pts->prep_ctrs chain.
__global__ __launch_bounds__(256) void conv_prep(Ptrs P, const int* __restrict__ fl,
                                                 float* __restrict__ Wf,
                                                 float4* __restrict__ pnt4,
                                                 float4* __restrict__ cent4,
                                                 int N, int M, int convB) {
    int b = blockIdx.x;
    if (b < convB) {
        int i = b * 256 + threadIdx.x;
        if (i >= WTOT) return;
        int j, off;
        if      (i < 16384)  { j = 2;  off = i; }
        else if (i < 32768)  { j = 3;  off = i - 16384; }
        else if (i < 49152)  { j = 4;  off = i - 32768; }
        else if (i < 65536)  { j = 5;  off = i - 49152; }
        else if (i < 131072) { j = 11; off = i - 65536; }
        else if (i < 196608) { j = 13; off = i - 131072; }
        else if (i < 212992) { j = 15; off = i - 196608; }
        else if (i < 213120) { j = 6;  off = i - 212992; }
        else if (i < 213248) { j = 7;  off = i - 213120; }
        else if (i < 213376) { j = 8;  off = i - 213248; }
        else if (i < 213504) { j = 9;  off = i - 213376; }
        else if (i < 213632) { j = 10; off = i - 213504; }
        else if (i < 214144) { j = 12; off = i - 213632; }
        else if (i < 214272) { j = 14; off = i - 214144; }
        else                 { j = 16; off = i - 214272; }
        Wf[i] = ldf(P.p[j], fl[j], off);
    } else {
        int i = (b - convB) * 256 + threadIdx.x;
        int f0 = fl[0];
        if (i < N) {
            float x = ldf(P.p[0], f0, 3 * i + 0);
            float y = ldf(P.p[0], f0, 3 * i + 1);
            float z = ldf(P.p[0], f0, 3 * i + 2);
            pnt4[i] = make_float4(x, y, z, norm32(x, y, z));
        }
        if (i < M) {
            int c = ldidx(P.p[17], fl[17], i);
            c = (c >= 0 && c < N) ? c : 0;
            float x = ldf(P.p[0], f0, 3 * c + 0);
            float y = ldf(P.p[0], f0, 3 * c + 1);
            float z = ldf(P.p[0], f0, 3 * c + 2);
            cent4[i] = make_float4(x, y, z, norm32(x, y, z));
        }
    }
}

// =================== kernel: ball query scan + top-32 select -> nbr_g (unchanged) ===================
__global__ __launch_bounds__(256) void ball_scan(
    const float4* __restrict__ pnt4,
    const float4* __restrict__ cent4,
    int N, int* __restrict__ nbr_g) {

    __shared__ u64 key[CAND];        // 16 KB
    __shared__ int s_cnt, s_ni[KMAX];

    int m = blockIdx.x, tid = threadIdx.x;
    float4 cc4 = cent4[m];

    if (tid == 0) s_cnt = 0;
    if (tid < KMAX) s_ni[tid] = -1;
    __syncthreads();

    for (int i = tid; i < N; i += 256) {
        float4 p = pnt4[i];
        float d2 = d2_32(cc4.x, cc4.y, cc4.z, cc4.w, p.x, p.y, p.z, p.w);
        if (d2 < 0.0901f) {
            float dist = d2_to_dist(d2);
            if (dist < 0.3f) {
                int pos = atomicAdd(&s_cnt, 1);
                if (pos < CAND)
                    key[pos] = ((u64)__float_as_uint(dist) << 32) | (unsigned)i;
            }
        }
    }
    __syncthreads();
    int cnt = min(s_cnt, CAND);

    for (int i = tid; i < cnt; i += 256) {
        u64 ki = key[i];
        int r = 0;
        for (int j = 0; j < cnt; ++j) r += (key[j] < ki) ? 1 : 0;
        if (r < KMAX) s_ni[r] = (int)(unsigned)(ki & 0xFFFFFFFFULL);
    }
    __syncthreads();
    if (tid < KMAX) nbr_g[m * KMAX + tid] = s_ni[tid];
}

// =================== kernel: attention + FFN -> cf (unchanged from v5, passing) ===================
#define NFT2(cc, kk) R[(cc) * NSTR2 + (kk)]
#define SKV2(kk, col) R[(kk) * KSTR + (col)]

__global__ __launch_bounds__(256, 4) void attn_ffn(
    const int* __restrict__ nbr_g,
    const void* __restrict__ feats,
    const void* __restrict__ idxc,
    const int* __restrict__ fl,
    const float* __restrict__ Wf,
    float* __restrict__ cf_out, int N, int M) {

    const float* Wqf = Wf;
    const float* Wkf = Wf + 16384;
    const float* Wvf = Wf + 32768;
    const float* Wof = Wf + 49152;
    const float* W1f = Wf + 65536;
    const float* W2f = Wf + 131072;
    const float* Pf  = Wf + 212992;

    __shared__ __align__(16) float R[128 * NSTR2];   // 36.9KB: nft[128][72] | s_kv[64][132]+tail
    __shared__ int   s_ni[2 * KMAX];
    __shared__ __align__(16) float s_cf[256], s_x[256];
    __shared__ float s_red[8];

    int tid = threadIdx.x;
    int lane = tid & 63, wv = tid >> 6;
    int center = tid >> 7, col = tid & 127;
    int m0 = blockIdx.x * 2;
    int f1 = fl[1], fi = fl[17];

    if (tid < 64) {
        int m2 = m0 + (tid >> 5);
        s_ni[tid] = (m2 < M) ? nbr_g[m2 * KMAX + (tid & 31)] : -1;
    }
    {
        int m2 = m0 + center; m2 = (m2 < M) ? m2 : (M - 1);
        int c = ldidx(idxc, fi, m2);
        c = (c >= 0 && c < N) ? c : 0;
        s_cf[tid] = ldf(feats, f1, (size_t)c * DIM + col);
    }
    __syncthreads();                                             // B1
    for (int t = tid; t < 64 * DIM; t += 256) {
        int kk2 = t >> 7, cc = t & 127;
        int idx = s_ni[kk2];
        float v = (idx >= 0 && idx < N) ? ldf(feats, f1, (size_t)idx * DIM + cc) : 0.0f;
        NFT2(cc, kk2) = v;
    }
    __syncthreads();                                             // B2

    // ---- K/V GEMM: thread = 8 k-rows (both centers' range) x 4 cols, both mats ----
    int kq = tid >> 5, cq = tid & 31;
    int k0 = kq * 8, c0 = cq * 4;
    float ka[8][4], va[8][4];
#pragma unroll
    for (int j = 0; j < 8; ++j)
#pragma unroll
        for (int cc2 = 0; cc2 < 4; ++cc2) { ka[j][cc2] = 0.0f; va[j][cc2] = 0.0f; }

#pragma unroll 2
    for (int i = 0; i < DIM; ++i) {
        float4 n0  = *(const float4*)&NFT2(i, k0);
        float4 n1  = *(const float4*)&NFT2(i, k0 + 4);
        float4 wk  = *(const float4*)&Wkf[i * DIM + c0];
        float4 wv4 = *(const float4*)&Wvf[i * DIM + c0];
        float nn[8] = {n0.x, n0.y, n0.z, n0.w, n1.x, n1.y, n1.z, n1.w};
#pragma unroll
        for (int j = 0; j < 8; ++j) {
            float nj = nn[j];
            ka[j][0] = fmaf(nj, wk.x, ka[j][0]);
            ka[j][1] = fmaf(nj, wk.y, ka[j][1]);
            ka[j][2] = fmaf(nj, wk.z, ka[j][2]);
            ka[j][3] = fmaf(nj, wk.w, ka[j][3]);
            va[j][0] = fmaf(nj, wv4.x, va[j][0]);
            va[j][1] = fmaf(nj, wv4.y, va[j][1]);
            va[j][2] = fmaf(nj, wv4.z, va[j][2]);
            va[j][3] = fmaf(nj, wv4.w, va[j][3]);
        }
    }
    __syncthreads();                                             // B3: nft dead, R reusable

    float* s_q    = R + 8448;    // tail of R: 64*132 = 8448
    float* s_attn = R + 8704;
    float* s_ao   = R + 8960;    // tail ends at 9216 = 128*72

#pragma unroll
    for (int j = 0; j < 8; ++j)
        *(float4*)&SKV2(k0 + j, c0) = make_float4(ka[j][0], ka[j][1], ka[j][2], ka[j][3]);
    // Q GEMM (all 256 threads: one output col per center)
    {
        float acc = 0.0f;
        const float* cfc = s_cf + center * 128;
#pragma unroll 4
        for (int i = 0; i < DIM; i += 4) {
            float4 a = *(const float4*)&cfc[i];
            acc = fmaf(a.x, Wqf[(i + 0) * DIM + col], acc);
            acc = fmaf(a.y, Wqf[(i + 1) * DIM + col], acc);
            acc = fmaf(a.z, Wqf[(i + 2) * DIM + col], acc);
            acc = fmaf(a.w, Wqf[(i + 3) * DIM + col], acc);
        }
        s_q[tid] = acc;
    }
    __syncthreads();                                             // B4

    // ---- QK + softmax: all 256 threads; head = 32 contiguous lanes ----
    {
        int h = (tid >> 5) & 3, kk = tid & 31;
        float s = 0.0f;
#pragma unroll
        for (int d = 0; d < 32; ++d)
            s = fmaf(s_q[center * 128 + h * 32 + d], SKV2(center * 32 + kk, h * 32 + d), s);
        s *= ATT_SCALE;
        if (s_ni[center * 32 + kk] < 0) s = -1e9f;
        float mx = s;
        for (int off = 16; off; off >>= 1) mx = fmaxf(mx, __shfl_xor(mx, off, 32));
        float e = expf(s - mx);
        float sm = e;
        for (int off = 16; off; off >>= 1) sm += __shfl_xor(sm, off, 32);
        sm = (sm > 0.0f) ? sm : 1.0f;
        s_attn[tid] = e / sm;
    }
    __syncthreads();                                             // B5: K reads done
#pragma unroll
    for (int j = 0; j < 8; ++j)
        *(float4*)&SKV2(k0 + j, c0) = make_float4(va[j][0], va[j][1], va[j][2], va[j][3]);
    __syncthreads();                                             // B6

    // ---- PV: all 256 threads ----
    {
        int h = (tid >> 5) & 3, d = tid & 31;
        float o = 0.0f;
#pragma unroll
        for (int kk = 0; kk < KMAX; ++kk)
            o = fmaf(s_attn[center * 128 + h * 32 + kk], SKV2(center * 32 + kk, h * 32 + d), o);
        s_ao[center * 128 + d * 4 + h] = o;
    }
    __syncthreads();                                             // B7

    // ---- Wo + LN1 (all 256 threads; per-center reduce over its 2 waves) ----
    float upd = Pf[0 + col];  // bo
    {
#pragma unroll 4
        for (int i = 0; i < DIM; i += 4) {
            float4 a = *(const float4*)&s_ao[center * 128 + i];
            upd = fmaf(a.x, Wof[(i + 0) * DIM + col], upd);
            upd = fmaf(a.y, Wof[(i + 1) * DIM + col], upd);
            upd = fmaf(a.z, Wof[(i + 2) * DIM + col], upd);
            upd = fmaf(a.w, Wof[(i + 3) * DIM + col], upd);
        }
        float sum = upd;
        for (int off = 32; off; off >>= 1) sum += __shfl_xor(sum, off, 64);
        if (lane == 0) s_red[wv] = sum;
    }
    __syncthreads();                                             // B8
    float mu = (s_red[center * 2] + s_red[center * 2 + 1]) * (1.0f / 128.0f);
    float xc = upd - mu;
    {
        float q2 = xc * xc;
        for (int off = 32; off; off >>= 1) q2 += __shfl_xor(q2, off, 64);
        if (lane == 0) s_red[4 + wv] = q2;
    }
    __syncthreads();                                             // B9
    float var = (s_red[4 + center * 2] + s_red[5 + center * 2]) * (1.0f / 128.0f);
    float cf1;
    {
        float rs = 1.0f / sqrtf(var + LN_EPS);
        float ln1 = fmaf(xc * rs, Pf[128 + col], Pf[256 + col]);  // n1w, n1b
        cf1 = s_cf[tid] + ln1;
        s_x[tid] = cf1;
    }
    __syncthreads();                                             // B10

    // ---- FFN1: 4 outputs/thread (s_h = R[0..1024), V dead) ----
    float* s_h = R;
#pragma unroll
    for (int jj = 0; jj < 4; ++jj) {
        int j = col + 128 * jj;
        float a = Pf[640 + j];  // b1
#pragma unroll 4
        for (int i = 0; i < DIM; i += 4) {
            float4 v = *(const float4*)&s_x[center * 128 + i];
            a = fmaf(v.x, W1f[(i + 0) * 512 + j], a);
            a = fmaf(v.y, W1f[(i + 1) * 512 + j], a);
            a = fmaf(v.z, W1f[(i + 2) * 512 + j], a);
            a = fmaf(v.w, W1f[(i + 3) * 512 + j], a);
        }
        s_h[center * 512 + j] = fmaxf(a, 0.0f);
    }
    __syncthreads();                                             // B11

    // ---- FFN2: one output/thread, split-K halves kept in v4's association ----
    float fa = Pf[1152 + col];  // b2
    {
        const float* hc = s_h + center * 512;
#pragma unroll 4
        for (int i = 0; i < 256; i += 4) {
            float4 v = *(const float4*)&hc[i];
            fa = fmaf(v.x, W2f[(i + 0) * DIM + col], fa);
            fa = fmaf(v.y, W2f[(i + 1) * DIM + col], fa);
            fa = fmaf(v.z, W2f[(i + 2) * DIM + col], fa);
            fa = fmaf(v.w, W2f[(i + 3) * DIM + col], fa);
        }
    }
    float fb = 0.0f;
    {
        const float* hc = s_h + center * 512;
#pragma unroll 4
        for (int i = 256; i < 512; i += 4) {
            float4 v = *(const float4*)&hc[i];
            fb = fmaf(v.x, W2f[(i + 0) * DIM + col], fb);
            fb = fmaf(v.y, W2f[(i + 1) * DIM + col], fb);
            fb = fmaf(v.z, W2f[(i + 2) * DIM + col], fb);
            fb = fmaf(v.w, W2f[(i + 3) * DIM + col], fb);
        }
    }
    float ffn = fa + fb;
    {
        float sum = ffn;
        for (int off = 32; off; off >>= 1) sum += __shfl_xor(sum, off, 64);
        if (lane == 0) s_red[wv] = sum;
    }
    __syncthreads();                                             // B12
    mu = (s_red[center * 2] + s_red[center * 2 + 1]) * (1.0f / 128.0f);
    xc = ffn - mu;
    {
        float q2 = xc * xc;
        for (int off = 32; off; off >>= 1) q2 += __shfl_xor(q2, off, 64);
        if (lane == 0) s_red[4 + wv] = q2;
    }
    __syncthreads();                                             // B13
    var = (s_red[4 + center * 2] + s_red[5 + center * 2]) * (1.0f / 128.0f);
    {
        float rs2 = 1.0f / sqrtf(var + LN_EPS);
        float ln2 = fmaf(xc * rs2, Pf[384 + col], Pf[512 + col]);  // n2w, n2b
        int m2 = m0 + center;
        if (m2 < M) cf_out[(size_t)m2 * DIM + col] = cf1 + ln2;
    }
}

// =================== kernel: KNN select + upsample, 2 points per wave ===================
// v6: wave owns points p0,p0+1; every cent4 load is shared between both points' d2 chains
// (halves L2 traffic + load/addr freight per point; 2 independent fma chains per load).
// Per-point: lane-strided visit order, fminf chain, 8-round threshold extraction, Tuse
// formula, pass-2 key set, rank-select, ascending wsum and upsample fma order are all
// IDENTICAL to v4 -> bit-exact. Fallback (cnt>64 or M<8) runs the proven full scan and
// writes its winners into s_srt so one shared epilogue serves both paths.
#define CSWAP(a, b) { if ((b) < (a)) { u64 t_ = (a); (a) = (b); (b) = t_; } }

static __device__ __forceinline__ float extract8(float vmn) {
    float vv = vmn, T = 0.0f;
#pragma unroll
    for (int e = 0; e < 8; ++e) {
        float mv = vv;
        for (int off = 32; off; off >>= 1) mv = fminf(mv, __shfl_xor(mv, off, 64));
        T = mv;
        if (vv == mv) vv = 3.4e38f;
    }
    return fmaxf(T, 0.0f) * 1.0000019073486328f;   // 1+2^-19 tie-capture margin
}

__global__ __launch_bounds__(256) void knn_select(
    const float4* __restrict__ pnt4,
    const float4* __restrict__ cent4,
    const float* __restrict__ cf,
    float* __restrict__ upg,          // = d_out, N x 128 f32
    int N, int M) {

    __shared__ u64 s_buf[4][2][64];
    __shared__ u64 s_srt[4][2][8];
    __shared__ int s_cnt[4][2];

    int tid = threadIdx.x;
    int lane = tid & 63, wv = tid >> 6;
    int p0 = blockIdx.x * 8 + wv * 2;
    bool ownA = (p0 < N), ownB = (p0 + 1 < N);

    float4 pa = make_float4(0.f, 0.f, 0.f, 0.f);
    float4 pb = make_float4(0.f, 0.f, 0.f, 0.f);
    if (ownA) pa = pnt4[p0];
    if (ownB) pb = pnt4[p0 + 1];

    if (lane < 2) s_cnt[wv][lane] = 0;
    __syncthreads();

    // ---- pass 1: per-lane min of raw d2, both points share each load ----
    float va = 3.4e38f, vb = 3.4e38f;
    for (int j = lane; j < M; j += 64) {
        float4 cc = cent4[j];
        va = fminf(va, d2_32(cc.x, cc.y, cc.z, cc.w, pa.x, pa.y, pa.z, pa.w));
        vb = fminf(vb, d2_32(cc.x, cc.y, cc.z, cc.w, pb.x, pb.y, pb.z, pb.w));
    }
    float Ta = extract8(va);
    float Tb = extract8(vb);

    // ---- pass 2: push exact keys for d2 <= T, per-point buffers ----
    for (int j = lane; j < M; j += 64) {
        float4 cc = cent4[j];
        float d2a = d2_32(cc.x, cc.y, cc.z, cc.w, pa.x, pa.y, pa.z, pa.w);
        float d2b = d2_32(cc.x, cc.y, cc.z, cc.w, pb.x, pb.y, pb.z, pb.w);
        if (d2a <= Ta) {
            float dist = d2_to_dist(d2a);
            u64 key = ((u64)__float_as_uint(dist) << 32) | (unsigned)j;
            int pos = atomicAdd(&s_cnt[wv][0], 1);
            if (pos < 64) s_buf[wv][0][pos] = key;
        }
        if (d2b <= Tb) {
            float dist = d2_to_dist(d2b);
            u64 key = ((u64)__float_as_uint(dist) << 32) | (unsigned)j;
            int pos = atomicAdd(&s_cnt[wv][1], 1);
            if (pos < 64) s_buf[wv][1][pos] = key;
        }
    }
    // wave-internal LDS dep; ds ops complete in order per wave

    int   ki[2][8];
    float w8[2][8];
    float wsum[2];

#pragma unroll
    for (int e = 0; e < 2; ++e) {
        int cnt = s_cnt[wv][e];          // broadcast read, wave-uniform
        if (cnt <= 64 && M >= 8) {
            // exact rank-8 select over the buffer -> s_srt ascending
            u64 myk = (lane < cnt) ? s_buf[wv][e][lane] : ~0ULL;
            int r = 0;
            for (int i = 0; i < cnt; ++i) {
                u64 o = s_buf[wv][e][i];
                r += (o < myk) ? 1 : 0;
            }
            if (lane < cnt && r < 8) s_srt[wv][e][r] = myk;
        } else {
            // fallback: proven full 8-deep scan + merge; winners -> s_srt ascending
            float4 pp = e ? pb : pa;
            u64 f0 = ~0ULL, f1_ = ~0ULL, f2_ = ~0ULL, f3 = ~0ULL,
                f4 = ~0ULL, f5 = ~0ULL, f6 = ~0ULL, f7 = ~0ULL;
            for (int j = lane; j < M; j += 64) {
                float4 cc = cent4[j];
                float dist = dist32(cc.x, cc.y, cc.z, cc.w, pp.x, pp.y, pp.z, pp.w);
                u64 key = ((u64)__float_as_uint(dist) << 32) | (unsigned)j;
                if (key < f7) {
                    f7 = key;
                    CSWAP(f6, f7); CSWAP(f5, f6); CSWAP(f4, f5); CSWAP(f3, f4);
                    CSWAP(f2_, f3); CSWAP(f1_, f2_); CSWAP(f0, f1_);
                }
            }
            int ptr2 = 0;
            u64 cur2 = f0;
#pragma unroll
            for (int e2 = 0; e2 < 8; ++e2) {
                u64 v = cur2;
                for (int off = 32; off; off >>= 1) {
                    u64 o = __shfl_down(v, off, 64);
                    v = (o < v) ? o : v;
                }
                u64 gm = __shfl(v, 0, 64);
                if (lane == 0) s_srt[wv][e][e2] = gm;
                if (cur2 == gm) {
                    ptr2++;
                    cur2 = (ptr2 == 1) ? f1_ : (ptr2 == 2) ? f2_ : (ptr2 == 3) ? f3 :
                           (ptr2 == 4) ? f4 : (ptr2 == 5) ? f5 : (ptr2 == 6) ? f6 :
                           (ptr2 == 7) ? f7 : ~0ULL;
                }
            }
        }
        // shared epilogue: walk sorted[0..7] ascending (bit-exact wsum order)
        float ws = 0.0f;
#pragma unroll
        for (int e2 = 0; e2 < 8; ++e2) {
            u64 gm = s_srt[wv][e][e2];
            float d = __uint_as_float((unsigned)(gm >> 32));
            int ci = (int)(unsigned)(gm & 0xFFFFFFFFULL);
            ci = (ci >= 0 && ci < M) ? ci : 0;
            float t = __fadd_rn(d, 1e-6f);
            float w = 1.0f / __fmul_rn(t, t);
            ws += w;
            ki[e][e2] = ci;
            w8[e][e2] = w;
        }
        wsum[e] = ws;
    }

    float invA = 1.0f / wsum[0];
    float invB = 1.0f / wsum[1];
#pragma unroll
    for (int k = 0; k < 8; ++k) { w8[0][k] *= invA; w8[1][k] *= invB; }

    // ---- upsample: lane owns cols lane and lane+64 (k ascending, bit-exact) ----
    int c0 = lane, c1 = lane + 64;
    float uA0 = 0.0f, uA1 = 0.0f, uB0 = 0.0f, uB1 = 0.0f;
#pragma unroll
    for (int k = 0; k < 8; ++k) {
        const float* row = cf + (size_t)ki[0][k] * DIM;
        uA0 = fmaf(w8[0][k], row[c0], uA0);
        uA1 = fmaf(w8[0][k], row[c1], uA1);
    }
#pragma unroll
    for (int k = 0; k < 8; ++k) {
        const float* row = cf + (size_t)ki[1][k] * DIM;
        uB0 = fmaf(w8[1][k], row[c0], uB0);
        uB1 = fmaf(w8[1][k], row[c1], uB1);
    }

    if (ownA) {
        upg[(size_t)p0 * DIM + c0] = uA0;
        upg[(size_t)p0 * DIM + c1] = uA1;
    }
    if (ownB) {
        upg[(size_t)(p0 + 1) * DIM + c0] = uB0;
        upg[(size_t)(p0 + 1) * DIM + c1] = uB1;
    }
}

// =================== kernel: tiled Wp GEMM + epilogue, in place over d_out ===================
__global__ __launch_bounds__(256) void wp_out(
    const float* __restrict__ Wf,
    const void* __restrict__ feats,
    const int* __restrict__ fl,
    float* __restrict__ out,          // holds up on entry, final output on exit
    int N) {

    const float* Wpf = Wf + 196608;
    const float* bpf = Wf + 212992 + 1280;

    __shared__ __align__(16) float s_up[PB][132];   // +4 pad: 16B-aligned rows, bank spread

    int tid = threadIdx.x;
    int p0 = blockIdx.x * PB;

    // stage up tile (32 pts x 128), zero-fill past N
    for (int f = tid; f < PB * 32; f += 256) {
        int p = f >> 5, i4 = (f & 31) << 2;
        float4 v = make_float4(0.f, 0.f, 0.f, 0.f);
        if (p0 + p < N) v = *(const float4*)&out[(size_t)(p0 + p) * DIM + i4];
        *(float4*)&s_up[p][i4] = v;
    }
    __syncthreads();

    // thread = 4 cols x 4 pts register tile
    int cq = tid & 31, pq = tid >> 5;
    int c0 = cq << 2;
    int pA = pq << 2;

    float a00 = 0.f, a01 = 0.f, a02 = 0.f, a03 = 0.f;
    float a10 = 0.f, a11 = 0.f, a12 = 0.f, a13 = 0.f;
    float a20 = 0.f, a21 = 0.f, a22 = 0.f, a23 = 0.f;
    float a30 = 0.f, a31 = 0.f, a32 = 0.f, a33 = 0.f;

#pragma unroll 4
    for (int i = 0; i < DIM; ++i) {
        float4 w = *(const float4*)&Wpf[(size_t)i * DIM + c0];
        float u0 = s_up[pA + 0][i];
        float u1 = s_up[pA + 1][i];
        float u2 = s_up[pA + 2][i];
        float u3 = s_up[pA + 3][i];
        a00 = fmaf(u0, w.x, a00); a01 = fmaf(u0, w.y, a01);
        a02 = fmaf(u0, w.z, a02); a03 = fmaf(u0, w.w, a03);
        a10 = fmaf(u1, w.x, a10); a11 = fmaf(u1, w.y, a11);
        a12 = fmaf(u1, w.z, a12); a13 = fmaf(u1, w.w, a13);
        a20 = fmaf(u2, w.x, a20); a21 = fmaf(u2, w.y, a21);
        a22 = fmaf(u2, w.z, a22); a23 = fmaf(u2, w.w, a23);
        a30 = fmaf(u3, w.x, a30); a31 = fmaf(u3, w.y, a31);
        a32 = fmaf(u3, w.z, a32); a33 = fmaf(u3, w.w, a33);
    }

    int f1v = fl[1];
    float4 bp4 = make_float4(bpf[c0 + 0], bpf[c0 + 1], bpf[c0 + 2], bpf[c0 + 3]);

    float accs[4][4] = {{a00, a01, a02, a03}, {a10, a11, a12, a13},
                        {a20, a21, a22, a23}, {a30, a31, a32, a33}};
#pragma unroll
    for (int a = 0; a < 4; ++a) {
        int p = p0 + pA + a;
        if (p < N) {
            float4 u = *(const float4*)&s_up[pA + a][c0];
            float4 o;
            o.x = ldf(feats, f1v, (size_t)p * DIM + c0 + 0) + u.x + fmaxf(bp4.x + accs[a][0], 0.0f);
            o.y = ldf(feats, f1v, (size_t)p * DIM + c0 + 1) + u.y + fmaxf(bp4.y + accs[a][1], 0.0f);
            o.z = ldf(feats, f1v, (size_t)p * DIM + c0 + 2) + u.z + fmaxf(bp4.z + accs[a][2], 0.0f);
            o.w = ldf(feats, f1v, (size_t)p * DIM + c0 + 3) + u.w + fmaxf(bp4.w + accs[a][3], 0.0f);
            *(float4*)&out[(size_t)p * DIM + c0] = o;
        }
    }
}

extern "C" void kernel_launch(void* const* d_in, const int* in_sizes, int n_in,
                              void* d_out, int out_size, void* d_ws, size_t ws_size,
                              hipStream_t stream) {
    int N = in_sizes[0] / 3;
    int M = in_sizes[17];

    Ptrs P;
    for (int j = 0; j < 18; ++j) { P.p[j] = d_in[j]; P.sz[j] = in_sizes[j]; }

    size_t off = 0;
    auto alloc = [&](size_t bytes) -> void* {
        off = (off + 255) & ~(size_t)255;
        void* p = (void*)((char*)d_ws + off);
        off += bytes;
        return p;
    };
    int*    fl    = (int*)alloc(32 * 4);
    float*  Wf    = (float*)alloc((size_t)WTOT * 4);          // 858 KB
    float4* pnt4  = (float4*)alloc((size_t)N * 16);           // 800 KB
    float4* cent4 = (float4*)alloc((size_t)M * 16);           //  40 KB
    float*  cfbuf = (float*)alloc((size_t)M * DIM * 4);       // 1.28 MB
    int*    nbr   = (int*)alloc((size_t)M * KMAX * 4);        // 320 KB (total ~3.3 MB)

    int convB = (WTOT + 255) / 256;
    int NM = (N > M) ? N : M;
    int prepB = (NM + 255) / 256;

    probe_dtypes<<<1, 32, 0, stream>>>(P, fl);
    conv_prep<<<convB + prepB, 256, 0, stream>>>(P, fl, Wf, pnt4, cent4, N, M, convB);
    ball_scan<<<M, 256, 0, stream>>>(pnt4, cent4, N, nbr);
    attn_ffn<<<(M + 1) / 2, 256, 0, stream>>>(nbr, d_in[1], d_in[17], fl, Wf, cfbuf, N, M);
    knn_select<<<(N + 7) / 8, 256, 0, stream>>>(pnt4, cent4, cfbuf, (float*)d_out, N, M);
    wp_out<<<(N + PB - 1) / PB, 256, 0, stream>>>(Wf, d_in[1], fl, (float*)d_out, N);
}